// Round 1
// baseline (1098.379 us; speedup 1.0000x reference)
//
#include <hip/hip_runtime.h>

// Mamba mixer forward, MI355X. B=2 L=4096 H=1024 ED=2048 N=16 R=64 K=4.
// Pipeline: cvt(fp32->bf16) -> GEMM1(in_proj, split hs/gate) -> conv1d+SiLU ->
// GEMM2(x_proj, split dtr/B/C) -> GEMM3(dt_proj + softplus) -> selective scan
// (fp32, 16-deep prefetch) -> gate -> GEMM4(out_proj) -> d_out fp32.

typedef float f32x4 __attribute__((ext_vector_type(4)));
typedef short short8 __attribute__((ext_vector_type(8)));

#define DEV __device__ __forceinline__

DEV float bf2f(unsigned short u) {
  union { unsigned int i; float f; } v; v.i = ((unsigned int)u) << 16; return v.f;
}
DEV unsigned short f2bf(float f) {
  union { float f; unsigned int i; } v; v.f = f;
  return (unsigned short)((v.i + 0x7fffu + ((v.i >> 16) & 1u)) >> 16);
}

DEV void gload_lds16(const void* g, void* l) {
  // async global->LDS, 16B/lane; LDS dest = wave-uniform base + lane*16
  __builtin_amdgcn_global_load_lds(
      (const __attribute__((address_space(1))) unsigned int*)g,
      (__attribute__((address_space(3))) unsigned int*)l, 16, 0, 0);
}

// inline-asm MFMA (avoids builtin operand-type ambiguity; HK-proven pattern)
DEV void mfma_bf16(f32x4& d, short8 a, short8 b) {
  asm("v_mfma_f32_16x16x32_bf16 %0, %1, %2, %0" : "+v"(d) : "v"(a), "v"(b));
}

// ---------------------------------------------------------------------------
// C[M,N] = A[M,K] * B[N,K]^T ; A,B bf16 (ushort), fp32 accum, fused epilogues.
// EPI 0: fp32 store to o_f32[M,N]
// EPI 1: col<2048 -> bf16 o_b16a[M,2048]; else bf16 o_b16b[M,2048] (in_proj split)
// EPI 2: col<64 -> bf16 o_b16a[M,64]; col<80 -> f32 oB[M,16]; else f32 oC[M,16]
// EPI 3: softplus(v + bias[col]) -> f32 o_f32[M,N]
// ---------------------------------------------------------------------------
template <int BM, int BN, int WM, int WN, int EPI>
__global__ __launch_bounds__(256) void gemm_bt_kernel(
    const unsigned short* __restrict__ A, const unsigned short* __restrict__ Bw,
    int M, int N, int Kd,
    float* __restrict__ o_f32, unsigned short* __restrict__ o_b16a,
    unsigned short* __restrict__ o_b16b, const float* __restrict__ bias,
    float* __restrict__ oB, float* __restrict__ oC)
{
  constexpr int MFR = BM / WM / 16;
  constexpr int NFR = BN / WN / 16;
  constexpr int TA = BM * 4;  // 16B chunks per A K-tile (BM x 32 bf16)
  constexpr int TB = BN * 4;
  __shared__ unsigned short lds[(BM + BN) * 32];

  const int tid  = threadIdx.x;
  const int wave = tid >> 6;
  const int lane = tid & 63;
  const int row  = lane & 15;
  const int g    = lane >> 4;
  const int rowBase = blockIdx.y * BM;
  const int colBase = blockIdx.x * BN;
  const int WROW = (wave / WN) * (BM / WM);
  const int WCOL = (wave % WN) * (BN / WN);

  f32x4 acc[MFR][NFR];
  const f32x4 fz = {0.f, 0.f, 0.f, 0.f};
#pragma unroll
  for (int i = 0; i < MFR; ++i)
#pragma unroll
    for (int j = 0; j < NFR; ++j) acc[i][j] = fz;

  for (int kk = 0; kk < Kd; kk += 32) {
#pragma unroll
    for (int c0 = 0; c0 < TA; c0 += 256) {
      int ch = c0 + tid;
      if (ch < TA)
        gload_lds16(A + (size_t)(rowBase + (ch >> 2)) * Kd + kk + (ch & 3) * 8,
                    (void*)(lds + (c0 + wave * 64) * 8));
    }
#pragma unroll
    for (int c0 = 0; c0 < TB; c0 += 256) {
      int ch = c0 + tid;
      if (ch < TB)
        gload_lds16(Bw + (size_t)(colBase + (ch >> 2)) * Kd + kk + (ch & 3) * 8,
                    (void*)(lds + BM * 32 + (c0 + wave * 64) * 8));
    }
    __syncthreads();  // drains vmcnt (global_load_lds) + barrier
    short8 af[MFR], bfr[NFR];
#pragma unroll
    for (int mi = 0; mi < MFR; ++mi)
      af[mi] = *(const short8*)(lds + (WROW + mi * 16 + row) * 32 + g * 8);
#pragma unroll
    for (int ni = 0; ni < NFR; ++ni)
      bfr[ni] = *(const short8*)(lds + BM * 32 + (WCOL + ni * 16 + row) * 32 + g * 8);
#pragma unroll
    for (int mi = 0; mi < MFR; ++mi)
#pragma unroll
      for (int ni = 0; ni < NFR; ++ni)
        mfma_bf16(acc[mi][ni], af[mi], bfr[ni]);
    __syncthreads();
  }

  // epilogue: C/D layout col=lane&15, row=4*(lane>>4)+reg  [m89/m91 verified]
#pragma unroll
  for (int mi = 0; mi < MFR; ++mi) {
#pragma unroll
    for (int ni = 0; ni < NFR; ++ni) {
      const int gcol = colBase + WCOL + ni * 16 + row;
#pragma unroll
      for (int r = 0; r < 4; ++r) {
        const int grow = rowBase + WROW + mi * 16 + g * 4 + r;
        float v = acc[mi][ni][r];
        if constexpr (EPI == 0) {
          o_f32[(size_t)grow * N + gcol] = v;
        } else if constexpr (EPI == 1) {
          if (gcol < 2048) o_b16a[(size_t)grow * 2048 + gcol] = f2bf(v);
          else             o_b16b[(size_t)grow * 2048 + (gcol - 2048)] = f2bf(v);
        } else if constexpr (EPI == 2) {
          if (gcol < 64)      o_b16a[(size_t)grow * 64 + gcol] = f2bf(v);
          else if (gcol < 80) oB[(size_t)grow * 16 + (gcol - 64)] = v;
          else                oC[(size_t)grow * 16 + (gcol - 80)] = v;
        } else {
          float x = v + bias[gcol];
          o_f32[(size_t)grow * N + gcol] = (x > 20.f) ? x : log1pf(__expf(x));
        }
      }
    }
  }
}

// ---------------------------------------------------------------------------
// fp32 -> bf16 convert, 8 elems/thread
__global__ __launch_bounds__(256) void cvt_bf16_kernel(
    const float* __restrict__ in, unsigned short* __restrict__ out, int n8)
{
  int i = blockIdx.x * 256 + threadIdx.x;
  if (i >= n8) return;
  const float4* p = (const float4*)(in + (size_t)i * 8);
  float4 a = p[0], b = p[1];
  float v[8] = {a.x, a.y, a.z, a.w, b.x, b.y, b.z, b.w};
  unsigned o[4];
#pragma unroll
  for (int q = 0; q < 4; ++q)
    o[q] = (unsigned)f2bf(v[2 * q]) | ((unsigned)f2bf(v[2 * q + 1]) << 16);
  *(uint4*)(out + (size_t)i * 8) = make_uint4(o[0], o[1], o[2], o[3]);
}

// ---------------------------------------------------------------------------
// causal depthwise conv1d (K=4) + SiLU. hsraw/hsb: [B*L][2048] bf16.
__global__ __launch_bounds__(256) void conv_silu_kernel(
    const unsigned short* __restrict__ hsraw, const float* __restrict__ cw,
    const float* __restrict__ cb, unsigned short* __restrict__ hsb)
{
  int idx = blockIdx.x * 256 + threadIdx.x;  // B*L*(ED/8) = 2^21
  int e0 = (idx & 255) * 8;
  int t  = (idx >> 8) & 4095;
  int b  = idx >> 20;
  float acc[8];
  float wv[4][8];
#pragma unroll
  for (int j = 0; j < 8; ++j) acc[j] = cb[e0 + j];
#pragma unroll
  for (int k = 0; k < 4; ++k)
#pragma unroll
    for (int j = 0; j < 8; ++j) wv[k][j] = cw[(e0 + j) * 4 + k];
#pragma unroll
  for (int k = 0; k < 4; ++k) {
    int tt = t - 3 + k;
    if (tt < 0) continue;
    uint4 v4 = *(const uint4*)(hsraw + ((size_t)(b * 4096 + tt)) * 2048 + e0);
    unsigned arr[4] = {v4.x, v4.y, v4.z, v4.w};
#pragma unroll
    for (int q = 0; q < 4; ++q) {
      acc[2 * q]     += wv[k][2 * q]     * bf2f((unsigned short)(arr[q] & 0xffffu));
      acc[2 * q + 1] += wv[k][2 * q + 1] * bf2f((unsigned short)(arr[q] >> 16));
    }
  }
  unsigned o[4];
#pragma unroll
  for (int q = 0; q < 4; ++q) {
    float a0 = acc[2 * q], a1 = acc[2 * q + 1];
    a0 = a0 / (1.f + __expf(-a0));
    a1 = a1 / (1.f + __expf(-a1));
    o[q] = (unsigned)f2bf(a0) | ((unsigned)f2bf(a1) << 16);
  }
  *(uint4*)(hsb + ((size_t)(b * 4096 + t)) * 2048 + e0) = make_uint4(o[0], o[1], o[2], o[3]);
}

// ---------------------------------------------------------------------------
// selective scan. 16 lanes per (b,e) group = one state n each. y written over
// delta in place. PF=16 prefetch pipeline (operands are L3-resident).
__global__ __launch_bounds__(256) void scan_kernel(
    float* __restrict__ dy, const unsigned short* __restrict__ hsb,
    const float* __restrict__ Bb, const float* __restrict__ Cb,
    const float* __restrict__ alog)
{
  constexpr int PF = 16;
  const int tid = threadIdx.x;
  const int n = tid & 15;
  const int G = blockIdx.x * 16 + (tid >> 4);  // 0..4095
  const int b = G >> 11, e = G & 2047;
  const float An = -__expf(alog[e * 16 + n]);
  size_t base = ((size_t)(b * 4096)) * 2048 + e;
  size_t bc   = ((size_t)(b * 4096)) * 16 + n;
  float h = 0.f;
  float dq[PF], uq[PF], Bq[PF], Cq[PF];
#pragma unroll
  for (int j = 0; j < PF; ++j) {
    size_t nb = base + (size_t)j * 2048, nc = bc + (size_t)j * 16;
    dq[j] = dy[nb]; uq[j] = bf2f(hsb[nb]); Bq[j] = Bb[nc]; Cq[j] = Cb[nc];
  }
  for (int tc = 0; tc < 4096; tc += PF) {
    float dn[PF], un[PF], Bn[PF], Cn[PF];
#pragma unroll
    for (int j = 0; j < PF; ++j) {  // prefetch next chunk (pads cover tail OOB)
      size_t nb = base + (size_t)(PF + j) * 2048, nc = bc + (size_t)(PF + j) * 16;
      dn[j] = dy[nb]; un[j] = bf2f(hsb[nb]); Bn[j] = Bb[nc]; Cn[j] = Cb[nc];
    }
#pragma unroll
    for (int j = 0; j < PF; ++j) {
      float dA = __expf(dq[j] * An);
      h = fmaf(dA, h, dq[j] * uq[j] * Bq[j]);
      float p = h * Cq[j];
      p += __shfl_xor(p, 1); p += __shfl_xor(p, 2);
      p += __shfl_xor(p, 4); p += __shfl_xor(p, 8);
      if (n == 0) dy[base + (size_t)j * 2048] = p;
    }
#pragma unroll
    for (int j = 0; j < PF; ++j) { dq[j] = dn[j]; uq[j] = un[j]; Bq[j] = Bn[j]; Cq[j] = Cn[j]; }
    base += (size_t)PF * 2048; bc += (size_t)PF * 16;
  }
}

// ---------------------------------------------------------------------------
// y2 = (y + hs*D) * silu(gate) -> bf16
__global__ __launch_bounds__(256) void gate_out_kernel(
    const float* __restrict__ y, const unsigned short* __restrict__ hsb,
    const unsigned short* __restrict__ gateb, const float* __restrict__ D,
    unsigned short* __restrict__ y2b)
{
  int idx = blockIdx.x * 256 + threadIdx.x;  // 2^21
  int e0 = (idx & 255) * 8;
  size_t off = (size_t)idx * 8;
  const float4* yp = (const float4*)(y + off);
  float4 ya = yp[0], yb = yp[1];
  uint4 hv = *(const uint4*)(hsb + off);
  uint4 gv = *(const uint4*)(gateb + off);
  float4 d0 = *(const float4*)(D + e0);
  float4 d1 = *(const float4*)(D + e0 + 4);
  float yv[8] = {ya.x, ya.y, ya.z, ya.w, yb.x, yb.y, yb.z, yb.w};
  float dv[8] = {d0.x, d0.y, d0.z, d0.w, d1.x, d1.y, d1.z, d1.w};
  unsigned ha[4] = {hv.x, hv.y, hv.z, hv.w};
  unsigned ga[4] = {gv.x, gv.y, gv.z, gv.w};
  unsigned o[4];
#pragma unroll
  for (int q = 0; q < 4; ++q) {
    float r[2];
#pragma unroll
    for (int s = 0; s < 2; ++s) {
      float hsv = bf2f((unsigned short)((s ? (ha[q] >> 16) : ha[q]) & 0xffffu));
      float gvv = bf2f((unsigned short)((s ? (ga[q] >> 16) : ga[q]) & 0xffffu));
      float val = yv[2 * q + s] + hsv * dv[2 * q + s];
      r[s] = val * (gvv / (1.f + __expf(-gvv)));
    }
    o[q] = (unsigned)f2bf(r[0]) | ((unsigned)f2bf(r[1]) << 16);
  }
  *(uint4*)(y2b + off) = make_uint4(o[0], o[1], o[2], o[3]);
}

// ---------------------------------------------------------------------------
extern "C" void kernel_launch(void* const* d_in, const int* in_sizes, int n_in,
                              void* d_out, int out_size, void* d_ws, size_t ws_size,
                              hipStream_t stream)
{
  const float* x    = (const float*)d_in[0];
  const float* w1   = (const float*)d_in[1];
  const float* cw   = (const float*)d_in[2];
  const float* cb   = (const float*)d_in[3];
  const float* xp   = (const float*)d_in[4];
  const float* dtw  = (const float*)d_in[5];
  const float* dtb  = (const float*)d_in[6];
  const float* alog = (const float*)d_in[7];
  const float* Dp   = (const float*)d_in[8];
  const float* wo   = (const float*)d_in[9];
  float* out = (float*)d_out;
  char* ws = (char*)d_ws;

  // workspace layout (bytes)
  const size_t o_xb    = 0;           // 16 MB  x bf16 [8192][1024]
  const size_t o_wb1   = 16777216;    //  8 MB  in_proj_w bf16 [4096][1024]
  const size_t o_xpb   = 25165824;    //  .4MB  x_proj_w bf16 [96][2048]
  const size_t o_dtwb  = 25559040;    //  .25MB dt_w bf16 [2048][64]
  const size_t o_wob   = 25821184;    //  4 MB  out_proj_w bf16 [1024][2048]
  const size_t o_hsraw = 30015488;    // 32 MB  pre-conv hs bf16 (reused as y2b)
  const size_t o_gate  = 63569920;    // 32 MB  gate bf16
  const size_t o_hsb   = 97124352;    // 32 MB  post-conv hs bf16
  const size_t o_dtrb  = 130678784;   //  1 MB  dtr bf16 [8192][64]
  const size_t o_Bb    = 131727360;   //  .5MB  B fp32 [8192][16]
  const size_t o_Cb    = 132251648;   //  .5MB  C fp32 [8192][16]
  const size_t o_delta = 132775936;   // 64 MB  delta/y fp32 [8192][2048] (+pad)
  const size_t WS_NEED = o_delta + 67108864 + 262144;  // pad covers scan prefetch OOB
  if (ws_size < WS_NEED) return;

  unsigned short* xb    = (unsigned short*)(ws + o_xb);
  unsigned short* wb1   = (unsigned short*)(ws + o_wb1);
  unsigned short* xpb   = (unsigned short*)(ws + o_xpb);
  unsigned short* dtwb  = (unsigned short*)(ws + o_dtwb);
  unsigned short* wob   = (unsigned short*)(ws + o_wob);
  unsigned short* hsraw = (unsigned short*)(ws + o_hsraw);
  unsigned short* gate  = (unsigned short*)(ws + o_gate);
  unsigned short* hsb   = (unsigned short*)(ws + o_hsb);
  unsigned short* dtrb  = (unsigned short*)(ws + o_dtrb);
  float* Bb    = (float*)(ws + o_Bb);
  float* Cb    = (float*)(ws + o_Cb);
  float* delta = (float*)(ws + o_delta);

  cvt_bf16_kernel<<<4096, 256, 0, stream>>>(x,   xb,   1048576);
  cvt_bf16_kernel<<<2048, 256, 0, stream>>>(w1,  wb1,  524288);
  cvt_bf16_kernel<<<96,   256, 0, stream>>>(xp,  xpb,  24576);
  cvt_bf16_kernel<<<64,   256, 0, stream>>>(dtw, dtwb, 16384);
  cvt_bf16_kernel<<<1024, 256, 0, stream>>>(wo,  wob,  262144);

  // GEMM1: xz = x @ in_proj_w^T -> split hs/gate
  gemm_bt_kernel<128,128,2,2,1><<<dim3(32,64), 256, 0, stream>>>(
      xb, wb1, 8192, 4096, 1024, nullptr, hsraw, gate, nullptr, nullptr, nullptr);
  // causal conv1d + SiLU
  conv_silu_kernel<<<8192, 256, 0, stream>>>(hsraw, cw, cb, hsb);
  // GEMM2: ssm = hs @ x_proj_w^T -> dtr(bf16) / B / C
  gemm_bt_kernel<64,96,4,1,2><<<dim3(1,128), 256, 0, stream>>>(
      hsb, xpb, 8192, 96, 2048, nullptr, dtrb, nullptr, nullptr, Bb, Cb);
  // GEMM3: delta = softplus(dtr @ dt_w^T + dt_b)
  gemm_bt_kernel<128,128,2,2,3><<<dim3(16,64), 256, 0, stream>>>(
      dtrb, dtwb, 8192, 2048, 64, delta, nullptr, nullptr, dtb, nullptr, nullptr);
  // selective scan (y over delta in place)
  scan_kernel<<<256, 256, 0, stream>>>(delta, hsb, Bb, Cb, alog);
  // y2 = (y + hs*D) * silu(gate)  (y2b reuses hsraw space)
  gate_out_kernel<<<8192, 256, 0, stream>>>(delta, hsb, gate, Dp, hsraw);
  // GEMM4: out = y2 @ out_proj_w^T
  gemm_bt_kernel<128,128,2,2,0><<<dim3(8,64), 256, 0, stream>>>(
      hsraw, wob, 8192, 1024, 2048, out, nullptr, nullptr, nullptr, nullptr, nullptr);
}

// Round 2
// 476.564 us; speedup vs baseline: 2.3048x; 2.3048x over previous
//
#include <hip/hip_runtime.h>

// Mamba mixer forward, MI355X. B=2 L=4096 H=1024 ED=2048 N=16 R=64 K=4.
// Pipeline: cvt(fp32->bf16) -> GEMM1(in_proj, split hs/gate) -> conv1d+SiLU ->
// GEMM2(x_proj, split dtr/B/C) -> GEMM3(dt_proj + softplus) ->
// 3-phase chunked selective scan (fp32) -> gate -> GEMM4(out_proj) -> fp32.

typedef float f32x4 __attribute__((ext_vector_type(4)));
typedef short short8 __attribute__((ext_vector_type(8)));

#define DEV __device__ __forceinline__

DEV float bf2f(unsigned short u) {
  union { unsigned int i; float f; } v; v.i = ((unsigned int)u) << 16; return v.f;
}
DEV unsigned short f2bf(float f) {
  union { float f; unsigned int i; } v; v.f = f;
  return (unsigned short)((v.i + 0x7fffu + ((v.i >> 16) & 1u)) >> 16);
}

DEV void gload_lds16(const void* g, void* l) {
  __builtin_amdgcn_global_load_lds(
      (const __attribute__((address_space(1))) unsigned int*)g,
      (__attribute__((address_space(3))) unsigned int*)l, 16, 0, 0);
}

DEV void mfma_bf16(f32x4& d, short8 a, short8 b) {
  asm("v_mfma_f32_16x16x32_bf16 %0, %1, %2, %0" : "+v"(d) : "v"(a), "v"(b));
}

// ---------------------------------------------------------------------------
template <int BM, int BN, int WM, int WN, int EPI>
__global__ __launch_bounds__(256) void gemm_bt_kernel(
    const unsigned short* __restrict__ A, const unsigned short* __restrict__ Bw,
    int M, int N, int Kd,
    float* __restrict__ o_f32, unsigned short* __restrict__ o_b16a,
    unsigned short* __restrict__ o_b16b, const float* __restrict__ bias,
    float* __restrict__ oB, float* __restrict__ oC)
{
  constexpr int MFR = BM / WM / 16;
  constexpr int NFR = BN / WN / 16;
  constexpr int TA = BM * 4;
  constexpr int TB = BN * 4;
  __shared__ unsigned short lds[(BM + BN) * 32];

  const int tid  = threadIdx.x;
  const int wave = tid >> 6;
  const int lane = tid & 63;
  const int row  = lane & 15;
  const int g    = lane >> 4;
  const int rowBase = blockIdx.y * BM;
  const int colBase = blockIdx.x * BN;
  const int WROW = (wave / WN) * (BM / WM);
  const int WCOL = (wave % WN) * (BN / WN);

  f32x4 acc[MFR][NFR];
  const f32x4 fz = {0.f, 0.f, 0.f, 0.f};
#pragma unroll
  for (int i = 0; i < MFR; ++i)
#pragma unroll
    for (int j = 0; j < NFR; ++j) acc[i][j] = fz;

  for (int kk = 0; kk < Kd; kk += 32) {
#pragma unroll
    for (int c0 = 0; c0 < TA; c0 += 256) {
      int ch = c0 + tid;
      if (ch < TA)
        gload_lds16(A + (size_t)(rowBase + (ch >> 2)) * Kd + kk + (ch & 3) * 8,
                    (void*)(lds + (c0 + wave * 64) * 8));
    }
#pragma unroll
    for (int c0 = 0; c0 < TB; c0 += 256) {
      int ch = c0 + tid;
      if (ch < TB)
        gload_lds16(Bw + (size_t)(colBase + (ch >> 2)) * Kd + kk + (ch & 3) * 8,
                    (void*)(lds + BM * 32 + (c0 + wave * 64) * 8));
    }
    __syncthreads();
    short8 af[MFR], bfr[NFR];
#pragma unroll
    for (int mi = 0; mi < MFR; ++mi)
      af[mi] = *(const short8*)(lds + (WROW + mi * 16 + row) * 32 + g * 8);
#pragma unroll
    for (int ni = 0; ni < NFR; ++ni)
      bfr[ni] = *(const short8*)(lds + BM * 32 + (WCOL + ni * 16 + row) * 32 + g * 8);
#pragma unroll
    for (int mi = 0; mi < MFR; ++mi)
#pragma unroll
      for (int ni = 0; ni < NFR; ++ni)
        mfma_bf16(acc[mi][ni], af[mi], bfr[ni]);
    __syncthreads();
  }

#pragma unroll
  for (int mi = 0; mi < MFR; ++mi) {
#pragma unroll
    for (int ni = 0; ni < NFR; ++ni) {
      const int gcol = colBase + WCOL + ni * 16 + row;
#pragma unroll
      for (int r = 0; r < 4; ++r) {
        const int grow = rowBase + WROW + mi * 16 + g * 4 + r;
        float v = acc[mi][ni][r];
        if constexpr (EPI == 0) {
          o_f32[(size_t)grow * N + gcol] = v;
        } else if constexpr (EPI == 1) {
          if (gcol < 2048) o_b16a[(size_t)grow * 2048 + gcol] = f2bf(v);
          else             o_b16b[(size_t)grow * 2048 + (gcol - 2048)] = f2bf(v);
        } else if constexpr (EPI == 2) {
          if (gcol < 64)      o_b16a[(size_t)grow * 64 + gcol] = f2bf(v);
          else if (gcol < 80) oB[(size_t)grow * 16 + (gcol - 64)] = v;
          else                oC[(size_t)grow * 16 + (gcol - 80)] = v;
        } else {
          float x = v + bias[gcol];
          o_f32[(size_t)grow * N + gcol] = (x > 20.f) ? x : log1pf(__expf(x));
        }
      }
    }
  }
}

// ---------------------------------------------------------------------------
__global__ __launch_bounds__(256) void cvt_bf16_kernel(
    const float* __restrict__ in, unsigned short* __restrict__ out, int n8)
{
  int i = blockIdx.x * 256 + threadIdx.x;
  if (i >= n8) return;
  const float4* p = (const float4*)(in + (size_t)i * 8);
  float4 a = p[0], b = p[1];
  float v[8] = {a.x, a.y, a.z, a.w, b.x, b.y, b.z, b.w};
  unsigned o[4];
#pragma unroll
  for (int q = 0; q < 4; ++q)
    o[q] = (unsigned)f2bf(v[2 * q]) | ((unsigned)f2bf(v[2 * q + 1]) << 16);
  *(uint4*)(out + (size_t)i * 8) = make_uint4(o[0], o[1], o[2], o[3]);
}

// ---------------------------------------------------------------------------
__global__ __launch_bounds__(256) void conv_silu_kernel(
    const unsigned short* __restrict__ hsraw, const float* __restrict__ cw,
    const float* __restrict__ cb, unsigned short* __restrict__ hsb)
{
  int idx = blockIdx.x * 256 + threadIdx.x;
  int e0 = (idx & 255) * 8;
  int t  = (idx >> 8) & 4095;
  int b  = idx >> 20;
  float acc[8];
  float wv[4][8];
#pragma unroll
  for (int j = 0; j < 8; ++j) acc[j] = cb[e0 + j];
#pragma unroll
  for (int k = 0; k < 4; ++k)
#pragma unroll
    for (int j = 0; j < 8; ++j) wv[k][j] = cw[(e0 + j) * 4 + k];
#pragma unroll
  for (int k = 0; k < 4; ++k) {
    int tt = t - 3 + k;
    if (tt < 0) continue;
    uint4 v4 = *(const uint4*)(hsraw + ((size_t)(b * 4096 + tt)) * 2048 + e0);
    unsigned arr[4] = {v4.x, v4.y, v4.z, v4.w};
#pragma unroll
    for (int q = 0; q < 4; ++q) {
      acc[2 * q]     += wv[k][2 * q]     * bf2f((unsigned short)(arr[q] & 0xffffu));
      acc[2 * q + 1] += wv[k][2 * q + 1] * bf2f((unsigned short)(arr[q] >> 16));
    }
  }
  unsigned o[4];
#pragma unroll
  for (int q = 0; q < 4; ++q) {
    float a0 = acc[2 * q], a1 = acc[2 * q + 1];
    a0 = a0 / (1.f + __expf(-a0));
    a1 = a1 / (1.f + __expf(-a1));
    o[q] = (unsigned)f2bf(a0) | ((unsigned)f2bf(a1) << 16);
  }
  *(uint4*)(hsb + ((size_t)(b * 4096 + t)) * 2048 + e0) = make_uint4(o[0], o[1], o[2], o[3]);
}

// ---------------------------------------------------------------------------
// 3-phase chunked selective scan. C=64 chunks of 64 steps; lane owns
// (b,e,chunk) with all N=16 states in registers.
// ---------------------------------------------------------------------------
__global__ __launch_bounds__(256) void scan_phase1(
    const float* __restrict__ delta, const unsigned short* __restrict__ hsb,
    const float* __restrict__ Bb, const float* __restrict__ alog,
    float* __restrict__ h_end, float* __restrict__ Ssum)
{
  __shared__ __align__(16) float Bs[64 * 16];
  const int tid = threadIdx.x;
  const int e = blockIdx.x * 256 + tid;
  const int c = blockIdx.y;
  const int b = blockIdx.z;
  const int t0 = c * 64;
  {
    const float* src = Bb + ((size_t)(b * 4096 + t0)) * 16;
#pragma unroll
    for (int k = 0; k < 4; ++k) Bs[tid + k * 256] = src[tid + k * 256];
  }
  float An[16];
  {
    const float4* ap = (const float4*)(alog + e * 16);
#pragma unroll
    for (int q = 0; q < 4; ++q) {
      float4 v = ap[q];
      An[4*q+0] = -__expf(v.x); An[4*q+1] = -__expf(v.y);
      An[4*q+2] = -__expf(v.z); An[4*q+3] = -__expf(v.w);
    }
  }
  __syncthreads();
  float h[16];
#pragma unroll
  for (int n = 0; n < 16; ++n) h[n] = 0.f;
  float sumd = 0.f;
  size_t base = ((size_t)(b * 4096 + t0)) * 2048 + e;
  float dd = delta[base];
  float uu = bf2f(hsb[base]);
  for (int j = 0; j < 64; ++j) {
    int jn = (j < 63) ? j + 1 : 63;
    float d_nxt = delta[base + (size_t)jn * 2048];
    float u_nxt = bf2f(hsb[base + (size_t)jn * 2048]);
    const float4* Bv = (const float4*)(Bs + j * 16);
    float4 b0 = Bv[0], b1 = Bv[1], b2 = Bv[2], b3 = Bv[3];
    float Bl[16] = {b0.x,b0.y,b0.z,b0.w, b1.x,b1.y,b1.z,b1.w,
                    b2.x,b2.y,b2.z,b2.w, b3.x,b3.y,b3.z,b3.w};
    sumd += dd;
    float du = dd * uu;
#pragma unroll
    for (int n = 0; n < 16; ++n)
      h[n] = fmaf(__expf(An[n] * dd), h[n], du * Bl[n]);
    dd = d_nxt; uu = u_nxt;
  }
  float* he = h_end + (((size_t)(b * 2048 + e)) * 64 + c) * 16;
#pragma unroll
  for (int q = 0; q < 4; ++q) {
    float4 v = {h[4*q], h[4*q+1], h[4*q+2], h[4*q+3]};
    *(float4*)(he + 4 * q) = v;
  }
  Ssum[((size_t)(b * 2048 + e)) * 64 + c] = sumd;
}

__global__ __launch_bounds__(256) void scan_phase2(
    const float* __restrict__ h_end, const float* __restrict__ Ssum,
    const float* __restrict__ alog, float* __restrict__ h_start)
{
  const int tid = threadIdx.x;
  const int n = tid & 15;
  const int G = blockIdx.x * 16 + (tid >> 4);
  const int e = G & 2047;
  const float An = -__expf(alog[e * 16 + n]);
  size_t hb = (size_t)G * 64 * 16 + n;
  size_t sb = (size_t)G * 64;
  float h = 0.f;
  constexpr int PF = 8;
  float hq[PF], Sq[PF];
#pragma unroll
  for (int j = 0; j < PF; ++j) { hq[j] = h_end[hb + (size_t)j * 16]; Sq[j] = Ssum[sb + j]; }
  for (int c0 = 0; c0 < 64; c0 += PF) {
    float hn[PF], Sn[PF];
#pragma unroll
    for (int j = 0; j < PF; ++j) {
      int cn = c0 + PF + j; cn = (cn < 64) ? cn : 63;
      hn[j] = h_end[hb + (size_t)cn * 16]; Sn[j] = Ssum[sb + cn];
    }
#pragma unroll
    for (int j = 0; j < PF; ++j) {
      h_start[hb + (size_t)(c0 + j) * 16] = h;
      h = fmaf(__expf(An * Sq[j]), h, hq[j]);
    }
#pragma unroll
    for (int j = 0; j < PF; ++j) { hq[j] = hn[j]; Sq[j] = Sn[j]; }
  }
}

__global__ __launch_bounds__(256) void scan_phase3(
    float* __restrict__ dy, const unsigned short* __restrict__ hsb,
    const float* __restrict__ Bb, const float* __restrict__ Cb,
    const float* __restrict__ alog, const float* __restrict__ h_start)
{
  __shared__ __align__(16) float Bs[64 * 16];
  __shared__ __align__(16) float Cs[64 * 16];
  const int tid = threadIdx.x;
  const int e = blockIdx.x * 256 + tid;
  const int c = blockIdx.y;
  const int b = blockIdx.z;
  const int t0 = c * 64;
  {
    const float* srcB = Bb + ((size_t)(b * 4096 + t0)) * 16;
    const float* srcC = Cb + ((size_t)(b * 4096 + t0)) * 16;
#pragma unroll
    for (int k = 0; k < 4; ++k) {
      Bs[tid + k * 256] = srcB[tid + k * 256];
      Cs[tid + k * 256] = srcC[tid + k * 256];
    }
  }
  float An[16];
  {
    const float4* ap = (const float4*)(alog + e * 16);
#pragma unroll
    for (int q = 0; q < 4; ++q) {
      float4 v = ap[q];
      An[4*q+0] = -__expf(v.x); An[4*q+1] = -__expf(v.y);
      An[4*q+2] = -__expf(v.z); An[4*q+3] = -__expf(v.w);
    }
  }
  float h[16];
  {
    const float4* hp = (const float4*)(h_start + (((size_t)(b * 2048 + e)) * 64 + c) * 16);
#pragma unroll
    for (int q = 0; q < 4; ++q) {
      float4 v = hp[q];
      h[4*q+0] = v.x; h[4*q+1] = v.y; h[4*q+2] = v.z; h[4*q+3] = v.w;
    }
  }
  __syncthreads();
  size_t base = ((size_t)(b * 4096 + t0)) * 2048 + e;
  float dd = dy[base];
  float uu = bf2f(hsb[base]);
  for (int j = 0; j < 64; ++j) {
    int jn = (j < 63) ? j + 1 : 63;
    float d_nxt = dy[base + (size_t)jn * 2048];
    float u_nxt = bf2f(hsb[base + (size_t)jn * 2048]);
    const float4* Bv = (const float4*)(Bs + j * 16);
    const float4* Cv = (const float4*)(Cs + j * 16);
    float4 b0 = Bv[0], b1 = Bv[1], b2 = Bv[2], b3 = Bv[3];
    float4 c0v = Cv[0], c1v = Cv[1], c2v = Cv[2], c3v = Cv[3];
    float Bl[16] = {b0.x,b0.y,b0.z,b0.w, b1.x,b1.y,b1.z,b1.w,
                    b2.x,b2.y,b2.z,b2.w, b3.x,b3.y,b3.z,b3.w};
    float Cl[16] = {c0v.x,c0v.y,c0v.z,c0v.w, c1v.x,c1v.y,c1v.z,c1v.w,
                    c2v.x,c2v.y,c2v.z,c2v.w, c3v.x,c3v.y,c3v.z,c3v.w};
    float du = dd * uu;
    float y = 0.f;
#pragma unroll
    for (int n = 0; n < 16; ++n) {
      h[n] = fmaf(__expf(An[n] * dd), h[n], du * Bl[n]);
      y = fmaf(h[n], Cl[n], y);
    }
    dy[base + (size_t)j * 2048] = y;
    dd = d_nxt; uu = u_nxt;
  }
}

// ---------------------------------------------------------------------------
__global__ __launch_bounds__(256) void gate_out_kernel(
    const float* __restrict__ y, const unsigned short* __restrict__ hsb,
    const unsigned short* __restrict__ gateb, const float* __restrict__ D,
    unsigned short* __restrict__ y2b)
{
  int idx = blockIdx.x * 256 + threadIdx.x;
  int e0 = (idx & 255) * 8;
  size_t off = (size_t)idx * 8;
  const float4* yp = (const float4*)(y + off);
  float4 ya = yp[0], yb = yp[1];
  uint4 hv = *(const uint4*)(hsb + off);
  uint4 gv = *(const uint4*)(gateb + off);
  float4 d0 = *(const float4*)(D + e0);
  float4 d1 = *(const float4*)(D + e0 + 4);
  float yv[8] = {ya.x, ya.y, ya.z, ya.w, yb.x, yb.y, yb.z, yb.w};
  float dv[8] = {d0.x, d0.y, d0.z, d0.w, d1.x, d1.y, d1.z, d1.w};
  unsigned ha[4] = {hv.x, hv.y, hv.z, hv.w};
  unsigned ga[4] = {gv.x, gv.y, gv.z, gv.w};
  unsigned o[4];
#pragma unroll
  for (int q = 0; q < 4; ++q) {
    float r[2];
#pragma unroll
    for (int s = 0; s < 2; ++s) {
      float hsv = bf2f((unsigned short)((s ? (ha[q] >> 16) : ha[q]) & 0xffffu));
      float gvv = bf2f((unsigned short)((s ? (ga[q] >> 16) : ga[q]) & 0xffffu));
      float val = yv[2 * q + s] + hsv * dv[2 * q + s];
      r[s] = val * (gvv / (1.f + __expf(-gvv)));
    }
    o[q] = (unsigned)f2bf(r[0]) | ((unsigned)f2bf(r[1]) << 16);
  }
  *(uint4*)(y2b + off) = make_uint4(o[0], o[1], o[2], o[3]);
}

// ---------------------------------------------------------------------------
extern "C" void kernel_launch(void* const* d_in, const int* in_sizes, int n_in,
                              void* d_out, int out_size, void* d_ws, size_t ws_size,
                              hipStream_t stream)
{
  const float* x    = (const float*)d_in[0];
  const float* w1   = (const float*)d_in[1];
  const float* cw   = (const float*)d_in[2];
  const float* cb   = (const float*)d_in[3];
  const float* xp   = (const float*)d_in[4];
  const float* dtw  = (const float*)d_in[5];
  const float* dtb  = (const float*)d_in[6];
  const float* alog = (const float*)d_in[7];
  const float* Dp   = (const float*)d_in[8];
  const float* wo   = (const float*)d_in[9];
  float* out = (float*)d_out;
  char* ws = (char*)d_ws;

  const size_t o_xb    = 0;           // 16 MB  x bf16 (reused: h_end fp32)
  const size_t o_wb1   = 16777216;    //  8 MB  in_proj_w bf16
  const size_t o_xpb   = 25165824;    //  .4MB  x_proj_w bf16
  const size_t o_dtwb  = 25559040;    //  .25MB dt_w bf16
  const size_t o_wob   = 25821184;    //  4 MB  out_proj_w bf16
  const size_t o_hsraw = 30015488;    // 32 MB  pre-conv hs (reused: h_start+S, y2b)
  const size_t o_gate  = 63569920;    // 32 MB  gate bf16
  const size_t o_hsb   = 97124352;    // 32 MB  post-conv hs bf16
  const size_t o_dtrb  = 130678784;   //  1 MB  dtr bf16
  const size_t o_Bb    = 131727360;   //  .5MB  B fp32
  const size_t o_Cb    = 132251648;   //  .5MB  C fp32
  const size_t o_delta = 132775936;   // 64 MB  delta/y fp32
  const size_t WS_NEED = o_delta + 67108864 + 262144;
  if (ws_size < WS_NEED) return;

  unsigned short* xb    = (unsigned short*)(ws + o_xb);
  unsigned short* wb1   = (unsigned short*)(ws + o_wb1);
  unsigned short* xpb   = (unsigned short*)(ws + o_xpb);
  unsigned short* dtwb  = (unsigned short*)(ws + o_dtwb);
  unsigned short* wob   = (unsigned short*)(ws + o_wob);
  unsigned short* hsraw = (unsigned short*)(ws + o_hsraw);
  unsigned short* gate  = (unsigned short*)(ws + o_gate);
  unsigned short* hsb   = (unsigned short*)(ws + o_hsb);
  unsigned short* dtrb  = (unsigned short*)(ws + o_dtrb);
  float* Bb    = (float*)(ws + o_Bb);
  float* Cb    = (float*)(ws + o_Cb);
  float* delta = (float*)(ws + o_delta);
  float* h_end   = (float*)(ws + o_xb);
  float* h_start = (float*)(ws + o_hsraw);
  float* Ssum    = (float*)(ws + o_hsraw + 16777216);

  cvt_bf16_kernel<<<4096, 256, 0, stream>>>(x,   xb,   1048576);
  cvt_bf16_kernel<<<2048, 256, 0, stream>>>(w1,  wb1,  524288);
  cvt_bf16_kernel<<<96,   256, 0, stream>>>(xp,  xpb,  24576);
  cvt_bf16_kernel<<<64,   256, 0, stream>>>(dtw, dtwb, 16384);
  cvt_bf16_kernel<<<1024, 256, 0, stream>>>(wo,  wob,  262144);

  gemm_bt_kernel<128,128,2,2,1><<<dim3(32,64), 256, 0, stream>>>(
      xb, wb1, 8192, 4096, 1024, nullptr, hsraw, gate, nullptr, nullptr, nullptr);
  conv_silu_kernel<<<8192, 256, 0, stream>>>(hsraw, cw, cb, hsb);
  gemm_bt_kernel<64,96,4,1,2><<<dim3(1,128), 256, 0, stream>>>(
      hsb, xpb, 8192, 96, 2048, nullptr, dtrb, nullptr, nullptr, Bb, Cb);
  gemm_bt_kernel<128,128,2,2,3><<<dim3(16,64), 256, 0, stream>>>(
      dtrb, dtwb, 8192, 2048, 64, delta, nullptr, nullptr, dtb, nullptr, nullptr);

  scan_phase1<<<dim3(8, 64, 2), 256, 0, stream>>>(delta, hsb, Bb, alog, h_end, Ssum);
  scan_phase2<<<256, 256, 0, stream>>>(h_end, Ssum, alog, h_start);
  scan_phase3<<<dim3(8, 64, 2), 256, 0, stream>>>(delta, hsb, Bb, Cb, alog, h_start);

  gate_out_kernel<<<8192, 256, 0, stream>>>(delta, hsb, gate, Dp, hsraw);
  gemm_bt_kernel<128,128,2,2,0><<<dim3(8,64), 256, 0, stream>>>(
      hsraw, wob, 8192, 1024, 2048, out, nullptr, nullptr, nullptr, nullptr, nullptr);
}

// Round 3
// 399.107 us; speedup vs baseline: 2.7521x; 1.1941x over previous
//
#include <hip/hip_runtime.h>

// Mamba mixer forward, MI355X. B=2 L=4096 H=1024 ED=2048 N=16 R=64 K=4.
// Pipeline: cvt(fp32->bf16) -> GEMM1(in_proj, split hs/gate) -> conv1d+SiLU ->
// GEMM2(x_proj, split dtr/B/C) -> GEMM3(dt_proj + fast softplus) ->
// 3-phase chunked selective scan (fp32) with gate/D/silu fused into phase3
// (writes y2 bf16 in-place over gate buffer) -> GEMM4(out_proj) -> fp32.

typedef float f32x4 __attribute__((ext_vector_type(4)));
typedef short short8 __attribute__((ext_vector_type(8)));

#define DEV __device__ __forceinline__

DEV float bf2f(unsigned short u) {
  union { unsigned int i; float f; } v; v.i = ((unsigned int)u) << 16; return v.f;
}
DEV unsigned short f2bf(float f) {
  union { float f; unsigned int i; } v; v.f = f;
  return (unsigned short)((v.i + 0x7fffu + ((v.i >> 16) & 1u)) >> 16);
}

DEV void gload_lds16(const void* g, void* l) {
  __builtin_amdgcn_global_load_lds(
      (const __attribute__((address_space(1))) unsigned int*)g,
      (__attribute__((address_space(3))) unsigned int*)l, 16, 0, 0);
}

DEV void mfma_bf16(f32x4& d, short8 a, short8 b) {
  asm("v_mfma_f32_16x16x32_bf16 %0, %1, %2, %0" : "+v"(d) : "v"(a), "v"(b));
}

// ---------------------------------------------------------------------------
// C[M,N] = A[M,K] * B[N,K]^T ; bf16 in, fp32 accum, fused epilogues (EPI).
// ---------------------------------------------------------------------------
template <int BM, int BN, int WM, int WN, int EPI>
__global__ __launch_bounds__(256) void gemm_bt_kernel(
    const unsigned short* __restrict__ A, const unsigned short* __restrict__ Bw,
    int M, int N, int Kd,
    float* __restrict__ o_f32, unsigned short* __restrict__ o_b16a,
    unsigned short* __restrict__ o_b16b, const float* __restrict__ bias,
    float* __restrict__ oB, float* __restrict__ oC)
{
  constexpr int MFR = BM / WM / 16;
  constexpr int NFR = BN / WN / 16;
  constexpr int TA = BM * 4;
  constexpr int TB = BN * 4;
  __shared__ unsigned short lds[(BM + BN) * 32];

  const int tid  = threadIdx.x;
  const int wave = tid >> 6;
  const int lane = tid & 63;
  const int row  = lane & 15;
  const int g    = lane >> 4;
  const int rowBase = blockIdx.y * BM;
  const int colBase = blockIdx.x * BN;
  const int WROW = (wave / WN) * (BM / WM);
  const int WCOL = (wave % WN) * (BN / WN);

  f32x4 acc[MFR][NFR];
  const f32x4 fz = {0.f, 0.f, 0.f, 0.f};
#pragma unroll
  for (int i = 0; i < MFR; ++i)
#pragma unroll
    for (int j = 0; j < NFR; ++j) acc[i][j] = fz;

  for (int kk = 0; kk < Kd; kk += 32) {
#pragma unroll
    for (int c0 = 0; c0 < TA; c0 += 256) {
      int ch = c0 + tid;
      if (ch < TA)
        gload_lds16(A + (size_t)(rowBase + (ch >> 2)) * Kd + kk + (ch & 3) * 8,
                    (void*)(lds + (c0 + wave * 64) * 8));
    }
#pragma unroll
    for (int c0 = 0; c0 < TB; c0 += 256) {
      int ch = c0 + tid;
      if (ch < TB)
        gload_lds16(Bw + (size_t)(colBase + (ch >> 2)) * Kd + kk + (ch & 3) * 8,
                    (void*)(lds + BM * 32 + (c0 + wave * 64) * 8));
    }
    __syncthreads();
    short8 af[MFR], bfr[NFR];
#pragma unroll
    for (int mi = 0; mi < MFR; ++mi)
      af[mi] = *(const short8*)(lds + (WROW + mi * 16 + row) * 32 + g * 8);
#pragma unroll
    for (int ni = 0; ni < NFR; ++ni)
      bfr[ni] = *(const short8*)(lds + BM * 32 + (WCOL + ni * 16 + row) * 32 + g * 8);
#pragma unroll
    for (int mi = 0; mi < MFR; ++mi)
#pragma unroll
      for (int ni = 0; ni < NFR; ++ni)
        mfma_bf16(acc[mi][ni], af[mi], bfr[ni]);
    __syncthreads();
  }

#pragma unroll
  for (int mi = 0; mi < MFR; ++mi) {
#pragma unroll
    for (int ni = 0; ni < NFR; ++ni) {
      const int gcol = colBase + WCOL + ni * 16 + row;
#pragma unroll
      for (int r = 0; r < 4; ++r) {
        const int grow = rowBase + WROW + mi * 16 + g * 4 + r;
        float v = acc[mi][ni][r];
        if constexpr (EPI == 0) {
          o_f32[(size_t)grow * N + gcol] = v;
        } else if constexpr (EPI == 1) {
          if (gcol < 2048) o_b16a[(size_t)grow * 2048 + gcol] = f2bf(v);
          else             o_b16b[(size_t)grow * 2048 + (gcol - 2048)] = f2bf(v);
        } else if constexpr (EPI == 2) {
          if (gcol < 64)      o_b16a[(size_t)grow * 64 + gcol] = f2bf(v);
          else if (gcol < 80) oB[(size_t)grow * 16 + (gcol - 64)] = v;
          else                oC[(size_t)grow * 16 + (gcol - 80)] = v;
        } else {
          // fast softplus: log1p(exp(x)) == log(1+exp(x)); 1+e^x >= 1 so no
          // cancellation; x>20 passthrough avoids overflow. ~8 VALU vs libm ~244.
          float x = v + bias[gcol];
          o_f32[(size_t)grow * N + gcol] = (x > 20.f) ? x : __logf(1.f + __expf(x));
        }
      }
    }
  }
}

// ---------------------------------------------------------------------------
__global__ __launch_bounds__(256) void cvt_bf16_kernel(
    const float* __restrict__ in, unsigned short* __restrict__ out, int n8)
{
  int i = blockIdx.x * 256 + threadIdx.x;
  if (i >= n8) return;
  const float4* p = (const float4*)(in + (size_t)i * 8);
  float4 a = p[0], b = p[1];
  float v[8] = {a.x, a.y, a.z, a.w, b.x, b.y, b.z, b.w};
  unsigned o[4];
#pragma unroll
  for (int q = 0; q < 4; ++q)
    o[q] = (unsigned)f2bf(v[2 * q]) | ((unsigned)f2bf(v[2 * q + 1]) << 16);
  *(uint4*)(out + (size_t)i * 8) = make_uint4(o[0], o[1], o[2], o[3]);
}

// ---------------------------------------------------------------------------
__global__ __launch_bounds__(256) void conv_silu_kernel(
    const unsigned short* __restrict__ hsraw, const float* __restrict__ cw,
    const float* __restrict__ cb, unsigned short* __restrict__ hsb)
{
  int idx = blockIdx.x * 256 + threadIdx.x;
  int e0 = (idx & 255) * 8;
  int t  = (idx >> 8) & 4095;
  int b  = idx >> 20;
  float acc[8];
  float wv[4][8];
#pragma unroll
  for (int j = 0; j < 8; ++j) acc[j] = cb[e0 + j];
#pragma unroll
  for (int k = 0; k < 4; ++k)
#pragma unroll
    for (int j = 0; j < 8; ++j) wv[k][j] = cw[(e0 + j) * 4 + k];
#pragma unroll
  for (int k = 0; k < 4; ++k) {
    int tt = t - 3 + k;
    if (tt < 0) continue;
    uint4 v4 = *(const uint4*)(hsraw + ((size_t)(b * 4096 + tt)) * 2048 + e0);
    unsigned arr[4] = {v4.x, v4.y, v4.z, v4.w};
#pragma unroll
    for (int q = 0; q < 4; ++q) {
      acc[2 * q]     += wv[k][2 * q]     * bf2f((unsigned short)(arr[q] & 0xffffu));
      acc[2 * q + 1] += wv[k][2 * q + 1] * bf2f((unsigned short)(arr[q] >> 16));
    }
  }
  unsigned o[4];
#pragma unroll
  for (int q = 0; q < 4; ++q) {
    float a0 = acc[2 * q], a1 = acc[2 * q + 1];
    a0 = a0 / (1.f + __expf(-a0));
    a1 = a1 / (1.f + __expf(-a1));
    o[q] = (unsigned)f2bf(a0) | ((unsigned)f2bf(a1) << 16);
  }
  *(uint4*)(hsb + ((size_t)(b * 4096 + t)) * 2048 + e0) = make_uint4(o[0], o[1], o[2], o[3]);
}

// ---------------------------------------------------------------------------
// 3-phase chunked selective scan. C=64 chunks of 64 steps; lane owns
// (b,e,chunk) with all N=16 states in registers.
// ---------------------------------------------------------------------------
__global__ __launch_bounds__(256) void scan_phase1(
    const float* __restrict__ delta, const unsigned short* __restrict__ hsb,
    const float* __restrict__ Bb, const float* __restrict__ alog,
    float* __restrict__ h_end, float* __restrict__ Ssum)
{
  __shared__ __align__(16) float Bs[64 * 16];
  const int tid = threadIdx.x;
  const int e = blockIdx.x * 256 + tid;
  const int c = blockIdx.y;
  const int b = blockIdx.z;
  const int t0 = c * 64;
  {
    const float* src = Bb + ((size_t)(b * 4096 + t0)) * 16;
#pragma unroll
    for (int k = 0; k < 4; ++k) Bs[tid + k * 256] = src[tid + k * 256];
  }
  float An[16];
  {
    const float4* ap = (const float4*)(alog + e * 16);
#pragma unroll
    for (int q = 0; q < 4; ++q) {
      float4 v = ap[q];
      An[4*q+0] = -__expf(v.x); An[4*q+1] = -__expf(v.y);
      An[4*q+2] = -__expf(v.z); An[4*q+3] = -__expf(v.w);
    }
  }
  __syncthreads();
  float h[16];
#pragma unroll
  for (int n = 0; n < 16; ++n) h[n] = 0.f;
  float sumd = 0.f;
  size_t base = ((size_t)(b * 4096 + t0)) * 2048 + e;
  float dd = delta[base];
  float uu = bf2f(hsb[base]);
  for (int j = 0; j < 64; ++j) {
    int jn = (j < 63) ? j + 1 : 63;
    float d_nxt = delta[base + (size_t)jn * 2048];
    float u_nxt = bf2f(hsb[base + (size_t)jn * 2048]);
    const float4* Bv = (const float4*)(Bs + j * 16);
    float4 b0 = Bv[0], b1 = Bv[1], b2 = Bv[2], b3 = Bv[3];
    float Bl[16] = {b0.x,b0.y,b0.z,b0.w, b1.x,b1.y,b1.z,b1.w,
                    b2.x,b2.y,b2.z,b2.w, b3.x,b3.y,b3.z,b3.w};
    sumd += dd;
    float du = dd * uu;
#pragma unroll
    for (int n = 0; n < 16; ++n)
      h[n] = fmaf(__expf(An[n] * dd), h[n], du * Bl[n]);
    dd = d_nxt; uu = u_nxt;
  }
  float* he = h_end + (((size_t)(b * 2048 + e)) * 64 + c) * 16;
#pragma unroll
  for (int q = 0; q < 4; ++q) {
    float4 v = {h[4*q], h[4*q+1], h[4*q+2], h[4*q+3]};
    *(float4*)(he + 4 * q) = v;
  }
  Ssum[((size_t)(b * 2048 + e)) * 64 + c] = sumd;
}

__global__ __launch_bounds__(256) void scan_phase2(
    const float* __restrict__ h_end, const float* __restrict__ Ssum,
    const float* __restrict__ alog, float* __restrict__ h_start)
{
  const int tid = threadIdx.x;
  const int n = tid & 15;
  const int G = blockIdx.x * 16 + (tid >> 4);
  const int e = G & 2047;
  const float An = -__expf(alog[e * 16 + n]);
  size_t hb = (size_t)G * 64 * 16 + n;
  size_t sb = (size_t)G * 64;
  float h = 0.f;
  constexpr int PF = 8;
  float hq[PF], Sq[PF];
#pragma unroll
  for (int j = 0; j < PF; ++j) { hq[j] = h_end[hb + (size_t)j * 16]; Sq[j] = Ssum[sb + j]; }
  for (int c0 = 0; c0 < 64; c0 += PF) {
    float hn[PF], Sn[PF];
#pragma unroll
    for (int j = 0; j < PF; ++j) {
      int cn = c0 + PF + j; cn = (cn < 64) ? cn : 63;
      hn[j] = h_end[hb + (size_t)cn * 16]; Sn[j] = Ssum[sb + cn];
    }
#pragma unroll
    for (int j = 0; j < PF; ++j) {
      h_start[hb + (size_t)(c0 + j) * 16] = h;
      h = fmaf(__expf(An * Sq[j]), h, hq[j]);
    }
#pragma unroll
    for (int j = 0; j < PF; ++j) { hq[j] = hn[j]; Sq[j] = Sn[j]; }
  }
}

// phase3 with fused output stage: y2 = (y + u*D) * silu(gate), bf16,
// written IN PLACE over the gate buffer (per-element read-then-write by the
// owning lane only -> no hazard; gate fully rewritten by GEMM1 each call).
__global__ __launch_bounds__(256) void scan_phase3(
    const float* __restrict__ delta, const unsigned short* __restrict__ hsb,
    const float* __restrict__ Bb, const float* __restrict__ Cb,
    const float* __restrict__ alog, const float* __restrict__ h_start,
    const float* __restrict__ Dv, unsigned short* __restrict__ gate_y2)
{
  __shared__ __align__(16) float Bs[64 * 16];
  __shared__ __align__(16) float Cs[64 * 16];
  const int tid = threadIdx.x;
  const int e = blockIdx.x * 256 + tid;
  const int c = blockIdx.y;
  const int b = blockIdx.z;
  const int t0 = c * 64;
  {
    const float* srcB = Bb + ((size_t)(b * 4096 + t0)) * 16;
    const float* srcC = Cb + ((size_t)(b * 4096 + t0)) * 16;
#pragma unroll
    for (int k = 0; k < 4; ++k) {
      Bs[tid + k * 256] = srcB[tid + k * 256];
      Cs[tid + k * 256] = srcC[tid + k * 256];
    }
  }
  float An[16];
  {
    const float4* ap = (const float4*)(alog + e * 16);
#pragma unroll
    for (int q = 0; q < 4; ++q) {
      float4 v = ap[q];
      An[4*q+0] = -__expf(v.x); An[4*q+1] = -__expf(v.y);
      An[4*q+2] = -__expf(v.z); An[4*q+3] = -__expf(v.w);
    }
  }
  const float De = Dv[e];
  float h[16];
  {
    const float4* hp = (const float4*)(h_start + (((size_t)(b * 2048 + e)) * 64 + c) * 16);
#pragma unroll
    for (int q = 0; q < 4; ++q) {
      float4 v = hp[q];
      h[4*q+0] = v.x; h[4*q+1] = v.y; h[4*q+2] = v.z; h[4*q+3] = v.w;
    }
  }
  __syncthreads();
  size_t base = ((size_t)(b * 4096 + t0)) * 2048 + e;
  float dd = delta[base];
  float uu = bf2f(hsb[base]);
  float gg = bf2f(gate_y2[base]);
  for (int j = 0; j < 64; ++j) {
    int jn = (j < 63) ? j + 1 : 63;
    float d_nxt = delta[base + (size_t)jn * 2048];
    float u_nxt = bf2f(hsb[base + (size_t)jn * 2048]);
    float g_nxt = bf2f(gate_y2[base + (size_t)jn * 2048]);
    const float4* Bv = (const float4*)(Bs + j * 16);
    const float4* Cv = (const float4*)(Cs + j * 16);
    float4 b0 = Bv[0], b1 = Bv[1], b2 = Bv[2], b3 = Bv[3];
    float4 c0v = Cv[0], c1v = Cv[1], c2v = Cv[2], c3v = Cv[3];
    float Bl[16] = {b0.x,b0.y,b0.z,b0.w, b1.x,b1.y,b1.z,b1.w,
                    b2.x,b2.y,b2.z,b2.w, b3.x,b3.y,b3.z,b3.w};
    float Cl[16] = {c0v.x,c0v.y,c0v.z,c0v.w, c1v.x,c1v.y,c1v.z,c1v.w,
                    c2v.x,c2v.y,c2v.z,c2v.w, c3v.x,c3v.y,c3v.z,c3v.w};
    float du = dd * uu;
    float y = 0.f;
#pragma unroll
    for (int n = 0; n < 16; ++n) {
      h[n] = fmaf(__expf(An[n] * dd), h[n], du * Bl[n]);
      y = fmaf(h[n], Cl[n], y);
    }
    float val = (y + uu * De) * (gg / (1.f + __expf(-gg)));
    gate_y2[base + (size_t)j * 2048] = f2bf(val);
    dd = d_nxt; uu = u_nxt; gg = g_nxt;
  }
}

// ---------------------------------------------------------------------------
extern "C" void kernel_launch(void* const* d_in, const int* in_sizes, int n_in,
                              void* d_out, int out_size, void* d_ws, size_t ws_size,
                              hipStream_t stream)
{
  const float* x    = (const float*)d_in[0];
  const float* w1   = (const float*)d_in[1];
  const float* cw   = (const float*)d_in[2];
  const float* cb   = (const float*)d_in[3];
  const float* xp   = (const float*)d_in[4];
  const float* dtw  = (const float*)d_in[5];
  const float* dtb  = (const float*)d_in[6];
  const float* alog = (const float*)d_in[7];
  const float* Dp   = (const float*)d_in[8];
  const float* wo   = (const float*)d_in[9];
  float* out = (float*)d_out;
  char* ws = (char*)d_ws;

  const size_t o_xb    = 0;           // 16 MB  x bf16 (reused: h_end fp32)
  const size_t o_wb1   = 16777216;    //  8 MB  in_proj_w bf16
  const size_t o_xpb   = 25165824;    //  .4MB  x_proj_w bf16
  const size_t o_dtwb  = 25559040;    //  .25MB dt_w bf16
  const size_t o_wob   = 25821184;    //  4 MB  out_proj_w bf16
  const size_t o_hsraw = 30015488;    // 32 MB  pre-conv hs (reused: h_start+Ssum)
  const size_t o_gate  = 63569920;    // 32 MB  gate bf16 (y2 written in place)
  const size_t o_hsb   = 97124352;    // 32 MB  post-conv hs bf16
  const size_t o_dtrb  = 130678784;   //  1 MB  dtr bf16
  const size_t o_Bb    = 131727360;   //  .5MB  B fp32
  const size_t o_Cb    = 132251648;   //  .5MB  C fp32
  const size_t o_delta = 132775936;   // 64 MB  delta fp32
  const size_t WS_NEED = o_delta + 67108864 + 262144;
  if (ws_size < WS_NEED) return;

  unsigned short* xb    = (unsigned short*)(ws + o_xb);
  unsigned short* wb1   = (unsigned short*)(ws + o_wb1);
  unsigned short* xpb   = (unsigned short*)(ws + o_xpb);
  unsigned short* dtwb  = (unsigned short*)(ws + o_dtwb);
  unsigned short* wob   = (unsigned short*)(ws + o_wob);
  unsigned short* hsraw = (unsigned short*)(ws + o_hsraw);
  unsigned short* gate  = (unsigned short*)(ws + o_gate);
  unsigned short* hsb   = (unsigned short*)(ws + o_hsb);
  unsigned short* dtrb  = (unsigned short*)(ws + o_dtrb);
  float* Bb    = (float*)(ws + o_Bb);
  float* Cb    = (float*)(ws + o_Cb);
  float* delta = (float*)(ws + o_delta);
  float* h_end   = (float*)(ws + o_xb);               // 16 MB (xb dead)
  float* h_start = (float*)(ws + o_hsraw);            // 16 MB (hsraw dead)
  float* Ssum    = (float*)(ws + o_hsraw + 16777216); //  1 MB

  cvt_bf16_kernel<<<4096, 256, 0, stream>>>(x,   xb,   1048576);
  cvt_bf16_kernel<<<2048, 256, 0, stream>>>(w1,  wb1,  524288);
  cvt_bf16_kernel<<<96,   256, 0, stream>>>(xp,  xpb,  24576);
  cvt_bf16_kernel<<<64,   256, 0, stream>>>(dtw, dtwb, 16384);
  cvt_bf16_kernel<<<1024, 256, 0, stream>>>(wo,  wob,  262144);

  gemm_bt_kernel<128,128,2,2,1><<<dim3(32,64), 256, 0, stream>>>(
      xb, wb1, 8192, 4096, 1024, nullptr, hsraw, gate, nullptr, nullptr, nullptr);
  conv_silu_kernel<<<8192, 256, 0, stream>>>(hsraw, cw, cb, hsb);
  gemm_bt_kernel<64,96,4,1,2><<<dim3(1,128), 256, 0, stream>>>(
      hsb, xpb, 8192, 96, 2048, nullptr, dtrb, nullptr, nullptr, Bb, Cb);
  gemm_bt_kernel<64,64,2,2,3><<<dim3(32,128), 256, 0, stream>>>(
      dtrb, dtwb, 8192, 2048, 64, delta, nullptr, nullptr, dtb, nullptr, nullptr);

  scan_phase1<<<dim3(8, 64, 2), 256, 0, stream>>>(delta, hsb, Bb, alog, h_end, Ssum);
  scan_phase2<<<256, 256, 0, stream>>>(h_end, Ssum, alog, h_start);
  scan_phase3<<<dim3(8, 64, 2), 256, 0, stream>>>(
      delta, hsb, Bb, Cb, alog, h_start, Dp, gate);

  gemm_bt_kernel<128,128,2,2,0><<<dim3(8,64), 256, 0, stream>>>(
      gate, wob, 8192, 1024, 2048, out, nullptr, nullptr, nullptr, nullptr, nullptr);
}

// Round 4
// 394.758 us; speedup vs baseline: 2.7824x; 1.0110x over previous
//
#include <hip/hip_runtime.h>

// Mamba mixer forward, MI355X. B=2 L=4096 H=1024 ED=2048 N=16 R=64 K=4.
// Pipeline: cvt(fp32->bf16) -> GEMM1(in_proj, split hs/gate) -> conv1d+SiLU ->
// GEMM2(x_proj, split dtr/B/C) -> GEMM3(dt_proj + fast softplus) ->
// 3-phase chunked selective scan (fp32) with gate/D/silu fused into phase3
// (writes y2 bf16 in-place over gate buffer) -> GEMM4(out_proj) -> fp32.
//
// R4: LDS 16B-chunk swizzle pos(row,g) = row*4 + (g ^ ((row>>1)&3)) applied
// BOTH sides (pre-swizzled global source for global_load_lds + swizzled
// ds_read addr) -> 8 consecutive lanes hit 8 distinct bank-spans (was 2).

typedef float f32x4 __attribute__((ext_vector_type(4)));
typedef short short8 __attribute__((ext_vector_type(8)));

#define DEV __device__ __forceinline__

DEV float bf2f(unsigned short u) {
  union { unsigned int i; float f; } v; v.i = ((unsigned int)u) << 16; return v.f;
}
DEV unsigned short f2bf(float f) {
  union { float f; unsigned int i; } v; v.f = f;
  return (unsigned short)((v.i + 0x7fffu + ((v.i >> 16) & 1u)) >> 16);
}

DEV void gload_lds16(const void* g, void* l) {
  __builtin_amdgcn_global_load_lds(
      (const __attribute__((address_space(1))) unsigned int*)g,
      (__attribute__((address_space(3))) unsigned int*)l, 16, 0, 0);
}

DEV void mfma_bf16(f32x4& d, short8 a, short8 b) {
  asm("v_mfma_f32_16x16x32_bf16 %0, %1, %2, %0" : "+v"(d) : "v"(a), "v"(b));
}

// ---------------------------------------------------------------------------
// C[M,N] = A[M,K] * B[N,K]^T ; bf16 in, fp32 accum, fused epilogues (EPI).
// LDS layout: tile row r's K-chunk g (8 bf16 = 16B) lives at 16B-chunk index
// r*4 + (g ^ ((r>>1)&3)).  WROW/WCOL/mi are multiples of 8 rows in all
// instantiations, so read-side swizzle = (lane>>4) ^ (((lane&15)>>1)&3).
// ---------------------------------------------------------------------------
template <int BM, int BN, int WM, int WN, int EPI>
__global__ __launch_bounds__(256) void gemm_bt_kernel(
    const unsigned short* __restrict__ A, const unsigned short* __restrict__ Bw,
    int M, int N, int Kd,
    float* __restrict__ o_f32, unsigned short* __restrict__ o_b16a,
    unsigned short* __restrict__ o_b16b, const float* __restrict__ bias,
    float* __restrict__ oB, float* __restrict__ oC)
{
  constexpr int MFR = BM / WM / 16;
  constexpr int NFR = BN / WN / 16;
  constexpr int TA = BM * 4;
  constexpr int TB = BN * 4;
  __shared__ unsigned short lds[(BM + BN) * 32];

  const int tid  = threadIdx.x;
  const int wave = tid >> 6;
  const int lane = tid & 63;
  const int row  = lane & 15;
  const int g    = lane >> 4;
  const int swz  = g ^ ((row >> 1) & 3);   // read-side chunk swizzle
  const int rowBase = blockIdx.y * BM;
  const int colBase = blockIdx.x * BN;
  const int WROW = (wave / WN) * (BM / WM);
  const int WCOL = (wave % WN) * (BN / WN);

  f32x4 acc[MFR][NFR];
  const f32x4 fz = {0.f, 0.f, 0.f, 0.f};
#pragma unroll
  for (int i = 0; i < MFR; ++i)
#pragma unroll
    for (int j = 0; j < NFR; ++j) acc[i][j] = fz;

  for (int kk = 0; kk < Kd; kk += 32) {
#pragma unroll
    for (int c0 = 0; c0 < TA; c0 += 256) {
      int ch = c0 + tid;
      if (ch < TA) {
        int r = ch >> 2;
        int gs = (ch & 3) ^ ((r >> 1) & 3);   // inverse placement permutation
        gload_lds16(A + (size_t)(rowBase + r) * Kd + kk + gs * 8,
                    (void*)(lds + (c0 + wave * 64) * 8));
      }
    }
#pragma unroll
    for (int c0 = 0; c0 < TB; c0 += 256) {
      int ch = c0 + tid;
      if (ch < TB) {
        int r = ch >> 2;
        int gs = (ch & 3) ^ ((r >> 1) & 3);
        gload_lds16(Bw + (size_t)(colBase + r) * Kd + kk + gs * 8,
                    (void*)(lds + BM * 32 + (c0 + wave * 64) * 8));
      }
    }
    __syncthreads();
    short8 af[MFR], bfr[NFR];
#pragma unroll
    for (int mi = 0; mi < MFR; ++mi)
      af[mi] = *(const short8*)(lds + (WROW + mi * 16 + row) * 32 + swz * 8);
#pragma unroll
    for (int ni = 0; ni < NFR; ++ni)
      bfr[ni] = *(const short8*)(lds + BM * 32 + (WCOL + ni * 16 + row) * 32 + swz * 8);
#pragma unroll
    for (int mi = 0; mi < MFR; ++mi)
#pragma unroll
      for (int ni = 0; ni < NFR; ++ni)
        mfma_bf16(acc[mi][ni], af[mi], bfr[ni]);
    __syncthreads();
  }

#pragma unroll
  for (int mi = 0; mi < MFR; ++mi) {
#pragma unroll
    for (int ni = 0; ni < NFR; ++ni) {
      const int gcol = colBase + WCOL + ni * 16 + row;
#pragma unroll
      for (int r = 0; r < 4; ++r) {
        const int grow = rowBase + WROW + mi * 16 + g * 4 + r;
        float v = acc[mi][ni][r];
        if constexpr (EPI == 0) {
          o_f32[(size_t)grow * N + gcol] = v;
        } else if constexpr (EPI == 1) {
          if (gcol < 2048) o_b16a[(size_t)grow * 2048 + gcol] = f2bf(v);
          else             o_b16b[(size_t)grow * 2048 + (gcol - 2048)] = f2bf(v);
        } else if constexpr (EPI == 2) {
          if (gcol < 64)      o_b16a[(size_t)grow * 64 + gcol] = f2bf(v);
          else if (gcol < 80) oB[(size_t)grow * 16 + (gcol - 64)] = v;
          else                oC[(size_t)grow * 16 + (gcol - 80)] = v;
        } else {
          // fast softplus: log(1+e^x), no cancellation; x>20 passthrough.
          float x = v + bias[gcol];
          o_f32[(size_t)grow * N + gcol] = (x > 20.f) ? x : __logf(1.f + __expf(x));
        }
      }
    }
  }
}

// ---------------------------------------------------------------------------
__global__ __launch_bounds__(256) void cvt_bf16_kernel(
    const float* __restrict__ in, unsigned short* __restrict__ out, int n8)
{
  int i = blockIdx.x * 256 + threadIdx.x;
  if (i >= n8) return;
  const float4* p = (const float4*)(in + (size_t)i * 8);
  float4 a = p[0], b = p[1];
  float v[8] = {a.x, a.y, a.z, a.w, b.x, b.y, b.z, b.w};
  unsigned o[4];
#pragma unroll
  for (int q = 0; q < 4; ++q)
    o[q] = (unsigned)f2bf(v[2 * q]) | ((unsigned)f2bf(v[2 * q + 1]) << 16);
  *(uint4*)(out + (size_t)i * 8) = make_uint4(o[0], o[1], o[2], o[3]);
}

// ---------------------------------------------------------------------------
__global__ __launch_bounds__(256) void conv_silu_kernel(
    const unsigned short* __restrict__ hsraw, const float* __restrict__ cw,
    const float* __restrict__ cb, unsigned short* __restrict__ hsb)
{
  int idx = blockIdx.x * 256 + threadIdx.x;
  int e0 = (idx & 255) * 8;
  int t  = (idx >> 8) & 4095;
  int b  = idx >> 20;
  float acc[8];
  float wv[4][8];
#pragma unroll
  for (int j = 0; j < 8; ++j) acc[j] = cb[e0 + j];
#pragma unroll
  for (int k = 0; k < 4; ++k)
#pragma unroll
    for (int j = 0; j < 8; ++j) wv[k][j] = cw[(e0 + j) * 4 + k];
#pragma unroll
  for (int k = 0; k < 4; ++k) {
    int tt = t - 3 + k;
    if (tt < 0) continue;
    uint4 v4 = *(const uint4*)(hsraw + ((size_t)(b * 4096 + tt)) * 2048 + e0);
    unsigned arr[4] = {v4.x, v4.y, v4.z, v4.w};
#pragma unroll
    for (int q = 0; q < 4; ++q) {
      acc[2 * q]     += wv[k][2 * q]     * bf2f((unsigned short)(arr[q] & 0xffffu));
      acc[2 * q + 1] += wv[k][2 * q + 1] * bf2f((unsigned short)(arr[q] >> 16));
    }
  }
  unsigned o[4];
#pragma unroll
  for (int q = 0; q < 4; ++q) {
    float a0 = acc[2 * q], a1 = acc[2 * q + 1];
    a0 = a0 / (1.f + __expf(-a0));
    a1 = a1 / (1.f + __expf(-a1));
    o[q] = (unsigned)f2bf(a0) | ((unsigned)f2bf(a1) << 16);
  }
  *(uint4*)(hsb + ((size_t)(b * 4096 + t)) * 2048 + e0) = make_uint4(o[0], o[1], o[2], o[3]);
}

// ---------------------------------------------------------------------------
// 3-phase chunked selective scan. C=64 chunks of 64 steps; lane owns
// (b,e,chunk) with all N=16 states in registers.
// ---------------------------------------------------------------------------
__global__ __launch_bounds__(256) void scan_phase1(
    const float* __restrict__ delta, const unsigned short* __restrict__ hsb,
    const float* __restrict__ Bb, const float* __restrict__ alog,
    float* __restrict__ h_end, float* __restrict__ Ssum)
{
  __shared__ __align__(16) float Bs[64 * 16];
  const int tid = threadIdx.x;
  const int e = blockIdx.x * 256 + tid;
  const int c = blockIdx.y;
  const int b = blockIdx.z;
  const int t0 = c * 64;
  {
    const float* src = Bb + ((size_t)(b * 4096 + t0)) * 16;
#pragma unroll
    for (int k = 0; k < 4; ++k) Bs[tid + k * 256] = src[tid + k * 256];
  }
  float An[16];
  {
    const float4* ap = (const float4*)(alog + e * 16);
#pragma unroll
    for (int q = 0; q < 4; ++q) {
      float4 v = ap[q];
      An[4*q+0] = -__expf(v.x); An[4*q+1] = -__expf(v.y);
      An[4*q+2] = -__expf(v.z); An[4*q+3] = -__expf(v.w);
    }
  }
  __syncthreads();
  float h[16];
#pragma unroll
  for (int n = 0; n < 16; ++n) h[n] = 0.f;
  float sumd = 0.f;
  size_t base = ((size_t)(b * 4096 + t0)) * 2048 + e;
  float dd = delta[base];
  float uu = bf2f(hsb[base]);
  for (int j = 0; j < 64; ++j) {
    int jn = (j < 63) ? j + 1 : 63;
    float d_nxt = delta[base + (size_t)jn * 2048];
    float u_nxt = bf2f(hsb[base + (size_t)jn * 2048]);
    const float4* Bv = (const float4*)(Bs + j * 16);
    float4 b0 = Bv[0], b1 = Bv[1], b2 = Bv[2], b3 = Bv[3];
    float Bl[16] = {b0.x,b0.y,b0.z,b0.w, b1.x,b1.y,b1.z,b1.w,
                    b2.x,b2.y,b2.z,b2.w, b3.x,b3.y,b3.z,b3.w};
    sumd += dd;
    float du = dd * uu;
#pragma unroll
    for (int n = 0; n < 16; ++n)
      h[n] = fmaf(__expf(An[n] * dd), h[n], du * Bl[n]);
    dd = d_nxt; uu = u_nxt;
  }
  float* he = h_end + (((size_t)(b * 2048 + e)) * 64 + c) * 16;
#pragma unroll
  for (int q = 0; q < 4; ++q) {
    float4 v = {h[4*q], h[4*q+1], h[4*q+2], h[4*q+3]};
    *(float4*)(he + 4 * q) = v;
  }
  Ssum[((size_t)(b * 2048 + e)) * 64 + c] = sumd;
}

__global__ __launch_bounds__(256) void scan_phase2(
    const float* __restrict__ h_end, const float* __restrict__ Ssum,
    const float* __restrict__ alog, float* __restrict__ h_start)
{
  const int tid = threadIdx.x;
  const int n = tid & 15;
  const int G = blockIdx.x * 16 + (tid >> 4);
  const int e = G & 2047;
  const float An = -__expf(alog[e * 16 + n]);
  size_t hb = (size_t)G * 64 * 16 + n;
  size_t sb = (size_t)G * 64;
  float h = 0.f;
  constexpr int PF = 8;
  float hq[PF], Sq[PF];
#pragma unroll
  for (int j = 0; j < PF; ++j) { hq[j] = h_end[hb + (size_t)j * 16]; Sq[j] = Ssum[sb + j]; }
  for (int c0 = 0; c0 < 64; c0 += PF) {
    float hn[PF], Sn[PF];
#pragma unroll
    for (int j = 0; j < PF; ++j) {
      int cn = c0 + PF + j; cn = (cn < 64) ? cn : 63;
      hn[j] = h_end[hb + (size_t)cn * 16]; Sn[j] = Ssum[sb + cn];
    }
#pragma unroll
    for (int j = 0; j < PF; ++j) {
      h_start[hb + (size_t)(c0 + j) * 16] = h;
      h = fmaf(__expf(An * Sq[j]), h, hq[j]);
    }
#pragma unroll
    for (int j = 0; j < PF; ++j) { hq[j] = hn[j]; Sq[j] = Sn[j]; }
  }
}

// phase3 with fused output stage: y2 = (y + u*D) * silu(gate), bf16,
// written IN PLACE over the gate buffer.
__global__ __launch_bounds__(256) void scan_phase3(
    const float* __restrict__ delta, const unsigned short* __restrict__ hsb,
    const float* __restrict__ Bb, const float* __restrict__ Cb,
    const float* __restrict__ alog, const float* __restrict__ h_start,
    const float* __restrict__ Dv, unsigned short* __restrict__ gate_y2)
{
  __shared__ __align__(16) float Bs[64 * 16];
  __shared__ __align__(16) float Cs[64 * 16];
  const int tid = threadIdx.x;
  const int e = blockIdx.x * 256 + tid;
  const int c = blockIdx.y;
  const int b = blockIdx.z;
  const int t0 = c * 64;
  {
    const float* srcB = Bb + ((size_t)(b * 4096 + t0)) * 16;
    const float* srcC = Cb + ((size_t)(b * 4096 + t0)) * 16;
#pragma unroll
    for (int k = 0; k < 4; ++k) {
      Bs[tid + k * 256] = srcB[tid + k * 256];
      Cs[tid + k * 256] = srcC[tid + k * 256];
    }
  }
  float An[16];
  {
    const float4* ap = (const float4*)(alog + e * 16);
#pragma unroll
    for (int q = 0; q < 4; ++q) {
      float4 v = ap[q];
      An[4*q+0] = -__expf(v.x); An[4*q+1] = -__expf(v.y);
      An[4*q+2] = -__expf(v.z); An[4*q+3] = -__expf(v.w);
    }
  }
  const float De = Dv[e];
  float h[16];
  {
    const float4* hp = (const float4*)(h_start + (((size_t)(b * 2048 + e)) * 64 + c) * 16);
#pragma unroll
    for (int q = 0; q < 4; ++q) {
      float4 v = hp[q];
      h[4*q+0] = v.x; h[4*q+1] = v.y; h[4*q+2] = v.z; h[4*q+3] = v.w;
    }
  }
  __syncthreads();
  size_t base = ((size_t)(b * 4096 + t0)) * 2048 + e;
  float dd = delta[base];
  float uu = bf2f(hsb[base]);
  float gg = bf2f(gate_y2[base]);
  for (int j = 0; j < 64; ++j) {
    int jn = (j < 63) ? j + 1 : 63;
    float d_nxt = delta[base + (size_t)jn * 2048];
    float u_nxt = bf2f(hsb[base + (size_t)jn * 2048]);
    float g_nxt = bf2f(gate_y2[base + (size_t)jn * 2048]);
    const float4* Bv = (const float4*)(Bs + j * 16);
    const float4* Cv = (const float4*)(Cs + j * 16);
    float4 b0 = Bv[0], b1 = Bv[1], b2 = Bv[2], b3 = Bv[3];
    float4 c0v = Cv[0], c1v = Cv[1], c2v = Cv[2], c3v = Cv[3];
    float Bl[16] = {b0.x,b0.y,b0.z,b0.w, b1.x,b1.y,b1.z,b1.w,
                    b2.x,b2.y,b2.z,b2.w, b3.x,b3.y,b3.z,b3.w};
    float Cl[16] = {c0v.x,c0v.y,c0v.z,c0v.w, c1v.x,c1v.y,c1v.z,c1v.w,
                    c2v.x,c2v.y,c2v.z,c2v.w, c3v.x,c3v.y,c3v.z,c3v.w};
    float du = dd * uu;
    float y = 0.f;
#pragma unroll
    for (int n = 0; n < 16; ++n) {
      h[n] = fmaf(__expf(An[n] * dd), h[n], du * Bl[n]);
      y = fmaf(h[n], Cl[n], y);
    }
    float val = (y + uu * De) * (gg / (1.f + __expf(-gg)));
    gate_y2[base + (size_t)j * 2048] = f2bf(val);
    dd = d_nxt; uu = u_nxt; gg = g_nxt;
  }
}

// ---------------------------------------------------------------------------
extern "C" void kernel_launch(void* const* d_in, const int* in_sizes, int n_in,
                              void* d_out, int out_size, void* d_ws, size_t ws_size,
                              hipStream_t stream)
{
  const float* x    = (const float*)d_in[0];
  const float* w1   = (const float*)d_in[1];
  const float* cw   = (const float*)d_in[2];
  const float* cb   = (const float*)d_in[3];
  const float* xp   = (const float*)d_in[4];
  const float* dtw  = (const float*)d_in[5];
  const float* dtb  = (const float*)d_in[6];
  const float* alog = (const float*)d_in[7];
  const float* Dp   = (const float*)d_in[8];
  const float* wo   = (const float*)d_in[9];
  float* out = (float*)d_out;
  char* ws = (char*)d_ws;

  const size_t o_xb    = 0;           // 16 MB  x bf16 (reused: h_end fp32)
  const size_t o_wb1   = 16777216;    //  8 MB  in_proj_w bf16
  const size_t o_xpb   = 25165824;    //  .4MB  x_proj_w bf16
  const size_t o_dtwb  = 25559040;    //  .25MB dt_w bf16
  const size_t o_wob   = 25821184;    //  4 MB  out_proj_w bf16
  const size_t o_hsraw = 30015488;    // 32 MB  pre-conv hs (reused: h_start+Ssum)
  const size_t o_gate  = 63569920;    // 32 MB  gate bf16 (y2 written in place)
  const size_t o_hsb   = 97124352;    // 32 MB  post-conv hs bf16
  const size_t o_dtrb  = 130678784;   //  1 MB  dtr bf16
  const size_t o_Bb    = 131727360;   //  .5MB  B fp32
  const size_t o_Cb    = 132251648;   //  .5MB  C fp32
  const size_t o_delta = 132775936;   // 64 MB  delta fp32
  const size_t WS_NEED = o_delta + 67108864 + 262144;
  if (ws_size < WS_NEED) return;

  unsigned short* xb    = (unsigned short*)(ws + o_xb);
  unsigned short* wb1   = (unsigned short*)(ws + o_wb1);
  unsigned short* xpb   = (unsigned short*)(ws + o_xpb);
  unsigned short* dtwb  = (unsigned short*)(ws + o_dtwb);
  unsigned short* wob   = (unsigned short*)(ws + o_wob);
  unsigned short* hsraw = (unsigned short*)(ws + o_hsraw);
  unsigned short* gate  = (unsigned short*)(ws + o_gate);
  unsigned short* hsb   = (unsigned short*)(ws + o_hsb);
  unsigned short* dtrb  = (unsigned short*)(ws + o_dtrb);
  float* Bb    = (float*)(ws + o_Bb);
  float* Cb    = (float*)(ws + o_Cb);
  float* delta = (float*)(ws + o_delta);
  float* h_end   = (float*)(ws + o_xb);               // 16 MB (xb dead)
  float* h_start = (float*)(ws + o_hsraw);            // 16 MB (hsraw dead)
  float* Ssum    = (float*)(ws + o_hsraw + 16777216); //  1 MB

  cvt_bf16_kernel<<<4096, 256, 0, stream>>>(x,   xb,   1048576);
  cvt_bf16_kernel<<<2048, 256, 0, stream>>>(w1,  wb1,  524288);
  cvt_bf16_kernel<<<96,   256, 0, stream>>>(xp,  xpb,  24576);
  cvt_bf16_kernel<<<64,   256, 0, stream>>>(dtw, dtwb, 16384);
  cvt_bf16_kernel<<<1024, 256, 0, stream>>>(wo,  wob,  262144);

  gemm_bt_kernel<128,128,2,2,1><<<dim3(32,64), 256, 0, stream>>>(
      xb, wb1, 8192, 4096, 1024, nullptr, hsraw, gate, nullptr, nullptr, nullptr);
  conv_silu_kernel<<<8192, 256, 0, stream>>>(hsraw, cw, cb, hsb);
  gemm_bt_kernel<64,96,4,1,2><<<dim3(1,128), 256, 0, stream>>>(
      hsb, xpb, 8192, 96, 2048, nullptr, dtrb, nullptr, nullptr, Bb, Cb);
  gemm_bt_kernel<64,64,2,2,3><<<dim3(32,128), 256, 0, stream>>>(
      dtrb, dtwb, 8192, 2048, 64, delta, nullptr, nullptr, dtb, nullptr, nullptr);

  scan_phase1<<<dim3(8, 64, 2), 256, 0, stream>>>(delta, hsb, Bb, alog, h_end, Ssum);
  scan_phase2<<<256, 256, 0, stream>>>(h_end, Ssum, alog, h_start);
  scan_phase3<<<dim3(8, 64, 2), 256, 0, stream>>>(
      delta, hsb, Bb, Cb, alog, h_start, Dp, gate);

  gemm_bt_kernel<128,128,2,2,0><<<dim3(8,64), 256, 0, stream>>>(
      gate, wob, 8192, 1024, 2048, out, nullptr, nullptr, nullptr, nullptr, nullptr);
}

// Round 5
// 386.111 us; speedup vs baseline: 2.8447x; 1.0224x over previous
//
#include <hip/hip_runtime.h>

// Mamba mixer forward, MI355X. B=2 L=4096 H=1024 ED=2048 N=16 R=64 K=4.
// Pipeline: cvt(fp32->bf16) -> GEMM1(in_proj, split hs/gate) -> conv1d+SiLU ->
// GEMM2(x_proj, split dtr/B/C) -> GEMM3(dt_proj + fast softplus) ->
// 3-phase chunked selective scan (fp32) with gate/D/silu fused into phase3
// (writes y2 bf16 in-place over gate buffer) -> GEMM4(out_proj) -> fp32.
//
// R4: LDS 16B-chunk swizzle (both-sides involution) -> bank conflicts = 0.
// R5: 3-buffer K-pipeline with COUNTED vmcnt (never 0 in steady state) +
//     raw s_barrier; loads stay in flight across barriers (T4 mechanism).

typedef float f32x4 __attribute__((ext_vector_type(4)));
typedef short short8 __attribute__((ext_vector_type(8)));

#define DEV __device__ __forceinline__

DEV float bf2f(unsigned short u) {
  union { unsigned int i; float f; } v; v.i = ((unsigned int)u) << 16; return v.f;
}
DEV unsigned short f2bf(float f) {
  union { float f; unsigned int i; } v; v.f = f;
  return (unsigned short)((v.i + 0x7fffu + ((v.i >> 16) & 1u)) >> 16);
}

DEV void gload_lds16(const void* g, void* l) {
  __builtin_amdgcn_global_load_lds(
      (const __attribute__((address_space(1))) unsigned int*)g,
      (__attribute__((address_space(3))) unsigned int*)l, 16, 0, 0);
}

DEV void mfma_bf16(f32x4& d, short8 a, short8 b) {
  asm("v_mfma_f32_16x16x32_bf16 %0, %1, %2, %0" : "+v"(d) : "v"(a), "v"(b));
}

template <int N> DEV void wait_vmcnt() {
  static_assert(N == 0 || N == 1 || N == 2 || N == 4 || N == 8, "unsupported");
  if constexpr (N == 0)      asm volatile("s_waitcnt vmcnt(0)" ::: "memory");
  else if constexpr (N == 1) asm volatile("s_waitcnt vmcnt(1)" ::: "memory");
  else if constexpr (N == 2) asm volatile("s_waitcnt vmcnt(2)" ::: "memory");
  else if constexpr (N == 4) asm volatile("s_waitcnt vmcnt(4)" ::: "memory");
  else                       asm volatile("s_waitcnt vmcnt(8)" ::: "memory");
}

// ---------------------------------------------------------------------------
// C[M,N] = A[M,K] * B[N,K]^T ; bf16 in, fp32 accum, fused epilogues (EPI).
// LDS: 3 K-tile buffers; chunk (row r, K-16B-group g) at index r*4+(g^((r>>1)&3)).
// Pipeline: stage(t+2) -> vmcnt(2*LPS) -> barrier -> compute(t) -> barrier.
// LPS = min per-wave loads/stage (wave 3), so the counted wait is never lax.
// ---------------------------------------------------------------------------
template <int BM, int BN, int WM, int WN, int EPI>
__global__ __launch_bounds__(256) void gemm_bt_kernel(
    const unsigned short* __restrict__ A, const unsigned short* __restrict__ Bw,
    int M, int N, int Kd,
    float* __restrict__ o_f32, unsigned short* __restrict__ o_b16a,
    unsigned short* __restrict__ o_b16b, const float* __restrict__ bias,
    float* __restrict__ oB, float* __restrict__ oC)
{
  constexpr int MFR = BM / WM / 16;
  constexpr int NFR = BN / WN / 16;
  constexpr int TA = BM * 4;              // 16B chunks per A K-tile
  constexpr int TB = BN * 4;
  constexpr int TILE = (BM + BN) * 32;    // elements per LDS buffer
  constexpr int LA3 = (TA > 192) ? ((TA - 193) / 256 + 1) : 0;  // wave-3 loads
  constexpr int LB3 = (TB > 192) ? ((TB - 193) / 256 + 1) : 0;
  constexpr int LPS = LA3 + LB3;          // min loads per stage per wave
  __shared__ unsigned short lds[TILE * 3];

  const int tid  = threadIdx.x;
  const int wave = tid >> 6;
  const int lane = tid & 63;
  const int row  = lane & 15;
  const int g    = lane >> 4;
  const int swz  = g ^ ((row >> 1) & 3);   // read-side chunk swizzle
  const int rowBase = blockIdx.y * BM;
  const int colBase = blockIdx.x * BN;
  const int WROW = (wave / WN) * (BM / WM);
  const int WCOL = (wave % WN) * (BN / WN);

  auto stage = [&](int kt, int bufbase) {
    const int kk = kt * 32;
#pragma unroll
    for (int c0 = 0; c0 < TA; c0 += 256) {
      int ch = c0 + tid;
      if (ch < TA) {
        int r = ch >> 2;
        int gs = (ch & 3) ^ ((r >> 1) & 3);   // inverse placement permutation
        gload_lds16(A + (size_t)(rowBase + r) * Kd + kk + gs * 8,
                    (void*)(lds + bufbase + (c0 + wave * 64) * 8));
      }
    }
#pragma unroll
    for (int c0 = 0; c0 < TB; c0 += 256) {
      int ch = c0 + tid;
      if (ch < TB) {
        int r = ch >> 2;
        int gs = (ch & 3) ^ ((r >> 1) & 3);
        gload_lds16(Bw + (size_t)(colBase + r) * Kd + kk + gs * 8,
                    (void*)(lds + bufbase + BM * 32 + (c0 + wave * 64) * 8));
      }
    }
  };

  f32x4 acc[MFR][NFR];
  const f32x4 fz = {0.f, 0.f, 0.f, 0.f};
#pragma unroll
  for (int i = 0; i < MFR; ++i)
#pragma unroll
    for (int j = 0; j < NFR; ++j) acc[i][j] = fz;

  const int nt = Kd / 32;
  stage(0, 0);
  stage(1, TILE);
  int cur = 0;
  for (int t = 0; t < nt; ++t) {
    if (t + 2 < nt) {
      int b2 = cur + 2; if (b2 >= 3) b2 -= 3;
      stage(t + 2, b2 * TILE);
      wait_vmcnt<2 * LPS>();      // own tile-t loads done; t+1,t+2 in flight
    } else if (t + 1 < nt) {
      wait_vmcnt<LPS>();
    } else {
      wait_vmcnt<0>();
    }
    __builtin_amdgcn_sched_barrier(0);
    __builtin_amdgcn_s_barrier();            // all waves: tile t resident
    __builtin_amdgcn_sched_barrier(0);
    const unsigned short* lb = lds + cur * TILE;
    short8 af[MFR], bfr[NFR];
#pragma unroll
    for (int mi = 0; mi < MFR; ++mi)
      af[mi] = *(const short8*)(lb + (WROW + mi * 16 + row) * 32 + swz * 8);
#pragma unroll
    for (int ni = 0; ni < NFR; ++ni)
      bfr[ni] = *(const short8*)(lb + BM * 32 + (WCOL + ni * 16 + row) * 32 + swz * 8);
#pragma unroll
    for (int mi = 0; mi < MFR; ++mi)
#pragma unroll
      for (int ni = 0; ni < NFR; ++ni)
        mfma_bf16(acc[mi][ni], af[mi], bfr[ni]);
    __builtin_amdgcn_sched_barrier(0);
    __builtin_amdgcn_s_barrier();            // protect buf t before overwrite
    cur += 1; if (cur >= 3) cur -= 3;
  }

#pragma unroll
  for (int mi = 0; mi < MFR; ++mi) {
#pragma unroll
    for (int ni = 0; ni < NFR; ++ni) {
      const int gcol = colBase + WCOL + ni * 16 + row;
#pragma unroll
      for (int r = 0; r < 4; ++r) {
        const int grow = rowBase + WROW + mi * 16 + g * 4 + r;
        float v = acc[mi][ni][r];
        if constexpr (EPI == 0) {
          o_f32[(size_t)grow * N + gcol] = v;
        } else if constexpr (EPI == 1) {
          if (gcol < 2048) o_b16a[(size_t)grow * 2048 + gcol] = f2bf(v);
          else             o_b16b[(size_t)grow * 2048 + (gcol - 2048)] = f2bf(v);
        } else if constexpr (EPI == 2) {
          if (gcol < 64)      o_b16a[(size_t)grow * 64 + gcol] = f2bf(v);
          else if (gcol < 80) oB[(size_t)grow * 16 + (gcol - 64)] = v;
          else                oC[(size_t)grow * 16 + (gcol - 80)] = v;
        } else {
          // fast softplus: log(1+e^x), no cancellation; x>20 passthrough.
          float x = v + bias[gcol];
          o_f32[(size_t)grow * N + gcol] = (x > 20.f) ? x : __logf(1.f + __expf(x));
        }
      }
    }
  }
}

// ---------------------------------------------------------------------------
__global__ __launch_bounds__(256) void cvt_bf16_kernel(
    const float* __restrict__ in, unsigned short* __restrict__ out, int n8)
{
  int i = blockIdx.x * 256 + threadIdx.x;
  if (i >= n8) return;
  const float4* p = (const float4*)(in + (size_t)i * 8);
  float4 a = p[0], b = p[1];
  float v[8] = {a.x, a.y, a.z, a.w, b.x, b.y, b.z, b.w};
  unsigned o[4];
#pragma unroll
  for (int q = 0; q < 4; ++q)
    o[q] = (unsigned)f2bf(v[2 * q]) | ((unsigned)f2bf(v[2 * q + 1]) << 16);
  *(uint4*)(out + (size_t)i * 8) = make_uint4(o[0], o[1], o[2], o[3]);
}

// ---------------------------------------------------------------------------
__global__ __launch_bounds__(256) void conv_silu_kernel(
    const unsigned short* __restrict__ hsraw, const float* __restrict__ cw,
    const float* __restrict__ cb, unsigned short* __restrict__ hsb)
{
  int idx = blockIdx.x * 256 + threadIdx.x;
  int e0 = (idx & 255) * 8;
  int t  = (idx >> 8) & 4095;
  int b  = idx >> 20;
  float acc[8];
  float wv[4][8];
#pragma unroll
  for (int j = 0; j < 8; ++j) acc[j] = cb[e0 + j];
#pragma unroll
  for (int k = 0; k < 4; ++k)
#pragma unroll
    for (int j = 0; j < 8; ++j) wv[k][j] = cw[(e0 + j) * 4 + k];
#pragma unroll
  for (int k = 0; k < 4; ++k) {
    int tt = t - 3 + k;
    if (tt < 0) continue;
    uint4 v4 = *(const uint4*)(hsraw + ((size_t)(b * 4096 + tt)) * 2048 + e0);
    unsigned arr[4] = {v4.x, v4.y, v4.z, v4.w};
#pragma unroll
    for (int q = 0; q < 4; ++q) {
      acc[2 * q]     += wv[k][2 * q]     * bf2f((unsigned short)(arr[q] & 0xffffu));
      acc[2 * q + 1] += wv[k][2 * q + 1] * bf2f((unsigned short)(arr[q] >> 16));
    }
  }
  unsigned o[4];
#pragma unroll
  for (int q = 0; q < 4; ++q) {
    float a0 = acc[2 * q], a1 = acc[2 * q + 1];
    a0 = a0 / (1.f + __expf(-a0));
    a1 = a1 / (1.f + __expf(-a1));
    o[q] = (unsigned)f2bf(a0) | ((unsigned)f2bf(a1) << 16);
  }
  *(uint4*)(hsb + ((size_t)(b * 4096 + t)) * 2048 + e0) = make_uint4(o[0], o[1], o[2], o[3]);
}

// ---------------------------------------------------------------------------
// 3-phase chunked selective scan. C=64 chunks of 64 steps; lane owns
// (b,e,chunk) with all N=16 states in registers.
// ---------------------------------------------------------------------------
__global__ __launch_bounds__(256) void scan_phase1(
    const float* __restrict__ delta, const unsigned short* __restrict__ hsb,
    const float* __restrict__ Bb, const float* __restrict__ alog,
    float* __restrict__ h_end, float* __restrict__ Ssum)
{
  __shared__ __align__(16) float Bs[64 * 16];
  const int tid = threadIdx.x;
  const int e = blockIdx.x * 256 + tid;
  const int c = blockIdx.y;
  const int b = blockIdx.z;
  const int t0 = c * 64;
  {
    const float* src = Bb + ((size_t)(b * 4096 + t0)) * 16;
#pragma unroll
    for (int k = 0; k < 4; ++k) Bs[tid + k * 256] = src[tid + k * 256];
  }
  float An[16];
  {
    const float4* ap = (const float4*)(alog + e * 16);
#pragma unroll
    for (int q = 0; q < 4; ++q) {
      float4 v = ap[q];
      An[4*q+0] = -__expf(v.x); An[4*q+1] = -__expf(v.y);
      An[4*q+2] = -__expf(v.z); An[4*q+3] = -__expf(v.w);
    }
  }
  __syncthreads();
  float h[16];
#pragma unroll
  for (int n = 0; n < 16; ++n) h[n] = 0.f;
  float sumd = 0.f;
  size_t base = ((size_t)(b * 4096 + t0)) * 2048 + e;
  float dd = delta[base];
  float uu = bf2f(hsb[base]);
  for (int j = 0; j < 64; ++j) {
    int jn = (j < 63) ? j + 1 : 63;
    float d_nxt = delta[base + (size_t)jn * 2048];
    float u_nxt = bf2f(hsb[base + (size_t)jn * 2048]);
    const float4* Bv = (const float4*)(Bs + j * 16);
    float4 b0 = Bv[0], b1 = Bv[1], b2 = Bv[2], b3 = Bv[3];
    float Bl[16] = {b0.x,b0.y,b0.z,b0.w, b1.x,b1.y,b1.z,b1.w,
                    b2.x,b2.y,b2.z,b2.w, b3.x,b3.y,b3.z,b3.w};
    sumd += dd;
    float du = dd * uu;
#pragma unroll
    for (int n = 0; n < 16; ++n)
      h[n] = fmaf(__expf(An[n] * dd), h[n], du * Bl[n]);
    dd = d_nxt; uu = u_nxt;
  }
  float* he = h_end + (((size_t)(b * 2048 + e)) * 64 + c) * 16;
#pragma unroll
  for (int q = 0; q < 4; ++q) {
    float4 v = {h[4*q], h[4*q+1], h[4*q+2], h[4*q+3]};
    *(float4*)(he + 4 * q) = v;
  }
  Ssum[((size_t)(b * 2048 + e)) * 64 + c] = sumd;
}

__global__ __launch_bounds__(256) void scan_phase2(
    const float* __restrict__ h_end, const float* __restrict__ Ssum,
    const float* __restrict__ alog, float* __restrict__ h_start)
{
  const int tid = threadIdx.x;
  const int n = tid & 15;
  const int G = blockIdx.x * 16 + (tid >> 4);
  const int e = G & 2047;
  const float An = -__expf(alog[e * 16 + n]);
  size_t hb = (size_t)G * 64 * 16 + n;
  size_t sb = (size_t)G * 64;
  float h = 0.f;
  constexpr int PF = 8;
  float hq[PF], Sq[PF];
#pragma unroll
  for (int j = 0; j < PF; ++j) { hq[j] = h_end[hb + (size_t)j * 16]; Sq[j] = Ssum[sb + j]; }
  for (int c0 = 0; c0 < 64; c0 += PF) {
    float hn[PF], Sn[PF];
#pragma unroll
    for (int j = 0; j < PF; ++j) {
      int cn = c0 + PF + j; cn = (cn < 64) ? cn : 63;
      hn[j] = h_end[hb + (size_t)cn * 16]; Sn[j] = Ssum[sb + cn];
    }
#pragma unroll
    for (int j = 0; j < PF; ++j) {
      h_start[hb + (size_t)(c0 + j) * 16] = h;
      h = fmaf(__expf(An * Sq[j]), h, hq[j]);
    }
#pragma unroll
    for (int j = 0; j < PF; ++j) { hq[j] = hn[j]; Sq[j] = Sn[j]; }
  }
}

// phase3 with fused output stage: y2 = (y + u*D) * silu(gate), bf16,
// written IN PLACE over the gate buffer.
__global__ __launch_bounds__(256) void scan_phase3(
    const float* __restrict__ delta, const unsigned short* __restrict__ hsb,
    const float* __restrict__ Bb, const float* __restrict__ Cb,
    const float* __restrict__ alog, const float* __restrict__ h_start,
    const float* __restrict__ Dv, unsigned short* __restrict__ gate_y2)
{
  __shared__ __align__(16) float Bs[64 * 16];
  __shared__ __align__(16) float Cs[64 * 16];
  const int tid = threadIdx.x;
  const int e = blockIdx.x * 256 + tid;
  const int c = blockIdx.y;
  const int b = blockIdx.z;
  const int t0 = c * 64;
  {
    const float* srcB = Bb + ((size_t)(b * 4096 + t0)) * 16;
    const float* srcC = Cb + ((size_t)(b * 4096 + t0)) * 16;
#pragma unroll
    for (int k = 0; k < 4; ++k) {
      Bs[tid + k * 256] = srcB[tid + k * 256];
      Cs[tid + k * 256] = srcC[tid + k * 256];
    }
  }
  float An[16];
  {
    const float4* ap = (const float4*)(alog + e * 16);
#pragma unroll
    for (int q = 0; q < 4; ++q) {
      float4 v = ap[q];
      An[4*q+0] = -__expf(v.x); An[4*q+1] = -__expf(v.y);
      An[4*q+2] = -__expf(v.z); An[4*q+3] = -__expf(v.w);
    }
  }
  const float De = Dv[e];
  float h[16];
  {
    const float4* hp = (const float4*)(h_start + (((size_t)(b * 2048 + e)) * 64 + c) * 16);
#pragma unroll
    for (int q = 0; q < 4; ++q) {
      float4 v = hp[q];
      h[4*q+0] = v.x; h[4*q+1] = v.y; h[4*q+2] = v.z; h[4*q+3] = v.w;
    }
  }
  __syncthreads();
  size_t base = ((size_t)(b * 4096 + t0)) * 2048 + e;
  float dd = delta[base];
  float uu = bf2f(hsb[base]);
  float gg = bf2f(gate_y2[base]);
  for (int j = 0; j < 64; ++j) {
    int jn = (j < 63) ? j + 1 : 63;
    float d_nxt = delta[base + (size_t)jn * 2048];
    float u_nxt = bf2f(hsb[base + (size_t)jn * 2048]);
    float g_nxt = bf2f(gate_y2[base + (size_t)jn * 2048]);
    const float4* Bv = (const float4*)(Bs + j * 16);
    const float4* Cv = (const float4*)(Cs + j * 16);
    float4 b0 = Bv[0], b1 = Bv[1], b2 = Bv[2], b3 = Bv[3];
    float4 c0v = Cv[0], c1v = Cv[1], c2v = Cv[2], c3v = Cv[3];
    float Bl[16] = {b0.x,b0.y,b0.z,b0.w, b1.x,b1.y,b1.z,b1.w,
                    b2.x,b2.y,b2.z,b2.w, b3.x,b3.y,b3.z,b3.w};
    float Cl[16] = {c0v.x,c0v.y,c0v.z,c0v.w, c1v.x,c1v.y,c1v.z,c1v.w,
                    c2v.x,c2v.y,c2v.z,c2v.w, c3v.x,c3v.y,c3v.z,c3v.w};
    float du = dd * uu;
    float y = 0.f;
#pragma unroll
    for (int n = 0; n < 16; ++n) {
      h[n] = fmaf(__expf(An[n] * dd), h[n], du * Bl[n]);
      y = fmaf(h[n], Cl[n], y);
    }
    float val = (y + uu * De) * (gg / (1.f + __expf(-gg)));
    gate_y2[base + (size_t)j * 2048] = f2bf(val);
    dd = d_nxt; uu = u_nxt; gg = g_nxt;
  }
}

// ---------------------------------------------------------------------------
extern "C" void kernel_launch(void* const* d_in, const int* in_sizes, int n_in,
                              void* d_out, int out_size, void* d_ws, size_t ws_size,
                              hipStream_t stream)
{
  const float* x    = (const float*)d_in[0];
  const float* w1   = (const float*)d_in[1];
  const float* cw   = (const float*)d_in[2];
  const float* cb   = (const float*)d_in[3];
  const float* xp   = (const float*)d_in[4];
  const float* dtw  = (const float*)d_in[5];
  const float* dtb  = (const float*)d_in[6];
  const float* alog = (const float*)d_in[7];
  const float* Dp   = (const float*)d_in[8];
  const float* wo   = (const float*)d_in[9];
  float* out = (float*)d_out;
  char* ws = (char*)d_ws;

  const size_t o_xb    = 0;           // 16 MB  x bf16 (reused: h_end fp32)
  const size_t o_wb1   = 16777216;    //  8 MB  in_proj_w bf16
  const size_t o_xpb   = 25165824;    //  .4MB  x_proj_w bf16
  const size_t o_dtwb  = 25559040;    //  .25MB dt_w bf16
  const size_t o_wob   = 25821184;    //  4 MB  out_proj_w bf16
  const size_t o_hsraw = 30015488;    // 32 MB  pre-conv hs (reused: h_start+Ssum)
  const size_t o_gate  = 63569920;    // 32 MB  gate bf16 (y2 written in place)
  const size_t o_hsb   = 97124352;    // 32 MB  post-conv hs bf16
  const size_t o_dtrb  = 130678784;   //  1 MB  dtr bf16
  const size_t o_Bb    = 131727360;   //  .5MB  B fp32
  const size_t o_Cb    = 132251648;   //  .5MB  C fp32
  const size_t o_delta = 132775936;   // 64 MB  delta fp32
  const size_t WS_NEED = o_delta + 67108864 + 262144;
  if (ws_size < WS_NEED) return;

  unsigned short* xb    = (unsigned short*)(ws + o_xb);
  unsigned short* wb1   = (unsigned short*)(ws + o_wb1);
  unsigned short* xpb   = (unsigned short*)(ws + o_xpb);
  unsigned short* dtwb  = (unsigned short*)(ws + o_dtwb);
  unsigned short* wob   = (unsigned short*)(ws + o_wob);
  unsigned short* hsraw = (unsigned short*)(ws + o_hsraw);
  unsigned short* gate  = (unsigned short*)(ws + o_gate);
  unsigned short* hsb   = (unsigned short*)(ws + o_hsb);
  unsigned short* dtrb  = (unsigned short*)(ws + o_dtrb);
  float* Bb    = (float*)(ws + o_Bb);
  float* Cb    = (float*)(ws + o_Cb);
  float* delta = (float*)(ws + o_delta);
  float* h_end   = (float*)(ws + o_xb);               // 16 MB (xb dead)
  float* h_start = (float*)(ws + o_hsraw);            // 16 MB (hsraw dead)
  float* Ssum    = (float*)(ws + o_hsraw + 16777216); //  1 MB

  cvt_bf16_kernel<<<4096, 256, 0, stream>>>(x,   xb,   1048576);
  cvt_bf16_kernel<<<2048, 256, 0, stream>>>(w1,  wb1,  524288);
  cvt_bf16_kernel<<<96,   256, 0, stream>>>(xp,  xpb,  24576);
  cvt_bf16_kernel<<<64,   256, 0, stream>>>(dtw, dtwb, 16384);
  cvt_bf16_kernel<<<1024, 256, 0, stream>>>(wo,  wob,  262144);

  gemm_bt_kernel<128,128,2,2,1><<<dim3(32,64), 256, 0, stream>>>(
      xb, wb1, 8192, 4096, 1024, nullptr, hsraw, gate, nullptr, nullptr, nullptr);
  conv_silu_kernel<<<8192, 256, 0, stream>>>(hsraw, cw, cb, hsb);
  gemm_bt_kernel<32,96,2,2,2><<<dim3(1,256), 256, 0, stream>>>(
      hsb, xpb, 8192, 96, 2048, nullptr, dtrb, nullptr, nullptr, Bb, Cb);
  gemm_bt_kernel<64,64,2,2,3><<<dim3(32,128), 256, 0, stream>>>(
      dtrb, dtwb, 8192, 2048, 64, delta, nullptr, nullptr, dtb, nullptr, nullptr);

  scan_phase1<<<dim3(8, 64, 2), 256, 0, stream>>>(delta, hsb, Bb, alog, h_end, Ssum);
  scan_phase2<<<256, 256, 0, stream>>>(h_end, Ssum, alog, h_start);
  scan_phase3<<<dim3(8, 64, 2), 256, 0, stream>>>(
      delta, hsb, Bb, Cb, alog, h_start, Dp, gate);

  gemm_bt_kernel<128,128,2,2,0><<<dim3(8,64), 256, 0, stream>>>(
      gate, wob, 8192, 1024, 2048, out, nullptr, nullptr, nullptr, nullptr, nullptr);
}

// Round 6
// 376.535 us; speedup vs baseline: 2.9171x; 1.0254x over previous
//
#include <hip/hip_runtime.h>

// Mamba mixer forward, MI355X. B=2 L=4096 H=1024 ED=2048 N=16 R=64 K=4.
// Pipeline: cvt(fp32->bf16) -> GEMM1(in_proj, 256^2 8-phase, split hs/gate) ->
// conv1d+SiLU -> GEMM2(x_proj) -> GEMM3(dt_proj + fast softplus) ->
// 3-phase chunked selective scan (fp32, gate/D/silu fused into phase3) ->
// GEMM4(out_proj) -> fp32.
//
// R6: GEMM1 ported to the 256x256 8-phase schedule (T2 swizzle + T3/T4
// counted-vmcnt pipeline + T5 setprio). LDS 128KB, 8 waves, BK=64, vmcnt(6)
// at phases 4/8 only; 3 half-tiles always in flight across raw s_barriers.

typedef float f32x4 __attribute__((ext_vector_type(4)));
typedef short short8 __attribute__((ext_vector_type(8)));
typedef unsigned short u16;

#define DEV __device__ __forceinline__

DEV float bf2f(u16 u) {
  union { unsigned int i; float f; } v; v.i = ((unsigned int)u) << 16; return v.f;
}
DEV u16 f2bf(float f) {
  union { float f; unsigned int i; } v; v.f = f;
  return (u16)((v.i + 0x7fffu + ((v.i >> 16) & 1u)) >> 16);
}

DEV void gload_lds16(const void* g, void* l) {
  __builtin_amdgcn_global_load_lds(
      (const __attribute__((address_space(1))) unsigned int*)g,
      (__attribute__((address_space(3))) unsigned int*)l, 16, 0, 0);
}

DEV void mfma_bf16(f32x4& d, short8 a, short8 b) {
  asm("v_mfma_f32_16x16x32_bf16 %0, %1, %2, %0" : "+v"(d) : "v"(a), "v"(b));
}

template <int N> DEV void wait_vmcnt() {
  if constexpr (N == 0)      asm volatile("s_waitcnt vmcnt(0)" ::: "memory");
  else if constexpr (N == 1) asm volatile("s_waitcnt vmcnt(1)" ::: "memory");
  else if constexpr (N == 2) asm volatile("s_waitcnt vmcnt(2)" ::: "memory");
  else if constexpr (N == 4) asm volatile("s_waitcnt vmcnt(4)" ::: "memory");
  else if constexpr (N == 6) asm volatile("s_waitcnt vmcnt(6)" ::: "memory");
  else                       asm volatile("s_waitcnt vmcnt(8)" ::: "memory");
}

#define SYNC_PRE() do { __builtin_amdgcn_s_barrier(); \
  asm volatile("s_waitcnt lgkmcnt(0)" ::: "memory"); \
  __builtin_amdgcn_sched_barrier(0); \
  __builtin_amdgcn_s_setprio(1); } while (0)
#define SYNC_POST() do { __builtin_amdgcn_s_setprio(0); \
  __builtin_amdgcn_sched_barrier(0); \
  __builtin_amdgcn_s_barrier(); } while (0)

// ---------------------------------------------------------------------------
// 256x256 8-phase GEMM: C[M,N] = A[M,K] * B[N,K]^T, bf16 in, fp32 accum.
// 512 threads = 8 waves (2M x 4N). BK=64; 2 K-tiles per iteration; per K-tile
// 4 phases = 4 C-quadrants (mh,nh) x 16 MFMA. LDS 128KB: [par][A 32K | B 32K],
// half-tiles of 128 rows. Chunk swizzle p = qc ^ (r&7) both sides.
// EPI 0: fp32 store. EPI 1: split bf16 at col 2048 (in_proj).
// ---------------------------------------------------------------------------
template <int EPI>
__global__ __launch_bounds__(512, 2) void gemm256_kernel(
    const u16* __restrict__ A, const u16* __restrict__ Bw,
    int M, int N, int Kd,
    float* __restrict__ o_f32, u16* __restrict__ o_b16a, u16* __restrict__ o_b16b)
{
  __shared__ u16 lds[65536];  // 128 KB
  const int tid  = threadIdx.x;
  const int wave = tid >> 6;
  const int lane = tid & 63;
  const int row  = lane & 15;
  const int g    = lane >> 4;
  const int wr   = wave >> 2;   // 0..1 (M)
  const int wc   = wave & 3;    // 0..3 (N)

  // XCD-aware block swizzle (grid % 8 == 0 for our shapes)
  const int nbx = N >> 8;
  const int nwg = gridDim.x;
  const int cpx = nwg >> 3;
  const int swzb = (blockIdx.x & 7) * cpx + (blockIdx.x >> 3);
  const int bx = swzb % nbx, by = swzb / nbx;
  const int rowBase = by * 256, colBase = bx * 256;

  // stage one half-tile (128 rows x 64 cols) = 2 gload_lds per thread.
  auto STAGE = [&](int isB, int h, int kt) {
    const u16* src = isB ? Bw : A;
    const int baseRow = (isB ? colBase : rowBase) + h * 128;
    const int ldsbase = (kt & 1) * 32768 + isB * 16384 + h * 8192;
    const int kk = kt * 64;
#pragma unroll
    for (int q = 0; q < 2; ++q) {
      int c = q * 512 + tid;
      int r = c >> 3;
      int qc = (c & 7) ^ (r & 7);     // inverse placement permutation
      gload_lds16(src + (size_t)(baseRow + r) * Kd + kk + qc * 8,
                  (void*)(lds + ldsbase + (q * 512 + wave * 64) * 8));
    }
  };

  f32x4 acc[8][4];
#pragma unroll
  for (int i = 0; i < 8; ++i)
#pragma unroll
    for (int j = 0; j < 4; ++j) acc[i][j] = (f32x4){0.f, 0.f, 0.f, 0.f};

  short8 rA[8], rB0[4], rB1[4];

#define LDA(PAR, MH) do { \
  _Pragma("unroll") for (int mi = 0; mi < 4; ++mi) \
  _Pragma("unroll") for (int ks = 0; ks < 2; ++ks) \
    rA[mi*2+ks] = *(const short8*)(lds + (PAR)*32768 + wr*8192 \
        + ((MH)*64 + mi*16 + row)*64 + (((ks*4 + g) ^ (row & 7))*8)); \
} while (0)

#define LDB(PAR, NH, RB) do { \
  _Pragma("unroll") for (int ni = 0; ni < 2; ++ni) \
  _Pragma("unroll") for (int ks = 0; ks < 2; ++ks) \
    (RB)[ni*2+ks] = *(const short8*)(lds + (PAR)*32768 + 16384 + (wc>>1)*8192 \
        + (((wc&1)*64 + (NH)*32 + ni*16 + row)*64) + (((ks*4 + g) ^ (row & 7))*8)); \
} while (0)

#define QUAD(MH, NH, RB) do { \
  _Pragma("unroll") for (int mi = 0; mi < 4; ++mi) \
  _Pragma("unroll") for (int ni = 0; ni < 2; ++ni) \
  _Pragma("unroll") for (int ks = 0; ks < 2; ++ks) \
    mfma_bf16(acc[(MH)*4+mi][(NH)*2+ni], rA[mi*2+ks], (RB)[ni*2+ks]); \
} while (0)

  const int nkt = Kd >> 6;
  const int niters = nkt >> 1;

  // prologue: kt0 fully + B01(kt1) + A0(kt1); vmcnt(6) completes kt0's 4 halves.
  STAGE(0, 0, 0); STAGE(0, 1, 0); STAGE(1, 0, 0); STAGE(1, 1, 0);
  STAGE(1, 0, 1); STAGE(1, 1, 1); STAGE(0, 0, 1);
  wait_vmcnt<6>();
  __builtin_amdgcn_s_barrier();

  for (int i = 0; i < niters; ++i) {
    const int kt0 = 2 * i, kt1 = 2 * i + 1;
    const bool pf = (i + 1 < niters);
    // P1: read A(mh0,kt0)+B(nh0,kt0); stage A1(kt1)
    LDA(0, 0); LDB(0, 0, rB0); STAGE(0, 1, kt1);
    SYNC_PRE(); QUAD(0, 0, rB0); SYNC_POST();
    // P2: read B(nh1,kt0)
    LDB(0, 1, rB1);
    SYNC_PRE(); QUAD(0, 1, rB1); SYNC_POST();
    // P3: read A(mh1,kt0); stage B0,B1(kt0+2)
    LDA(0, 1);
    if (pf) { STAGE(1, 0, kt0 + 2); STAGE(1, 1, kt0 + 2); }
    SYNC_PRE(); QUAD(1, 0, rB0); SYNC_POST();
    // P4: stage A0(kt0+2); counted vmcnt -> kt1 halves resident
    if (pf) { STAGE(0, 0, kt0 + 2); wait_vmcnt<6>(); } else { wait_vmcnt<0>(); }
    SYNC_PRE(); QUAD(1, 1, rB1); SYNC_POST();
    // P5: read A(mh0,kt1)+B(nh0,kt1); stage A1(kt0+2)
    LDA(1, 0); LDB(1, 0, rB0);
    if (pf) STAGE(0, 1, kt0 + 2);
    SYNC_PRE(); QUAD(0, 0, rB0); SYNC_POST();
    // P6: read B(nh1,kt1)
    LDB(1, 1, rB1);
    SYNC_PRE(); QUAD(0, 1, rB1); SYNC_POST();
    // P7: read A(mh1,kt1); stage B0,B1(kt1+2)
    LDA(1, 1);
    if (pf) { STAGE(1, 0, kt1 + 2); STAGE(1, 1, kt1 + 2); }
    SYNC_PRE(); QUAD(1, 0, rB0); SYNC_POST();
    // P8: stage A0(kt1+2); counted vmcnt -> next kt0 halves resident
    if (pf) { STAGE(0, 0, kt1 + 2); wait_vmcnt<6>(); } else { wait_vmcnt<0>(); }
    SYNC_PRE(); QUAD(1, 1, rB1); SYNC_POST();
  }
#undef LDA
#undef LDB
#undef QUAD

  // epilogue: C/D layout col=lane&15, row=4*(lane>>4)+reg
#pragma unroll
  for (int mf = 0; mf < 8; ++mf) {
    const int growb = rowBase + wr * 128 + (mf >> 2) * 64 + (mf & 3) * 16 + g * 4;
#pragma unroll
    for (int nf = 0; nf < 4; ++nf) {
      const int gcol = colBase + wc * 64 + (nf >> 1) * 32 + (nf & 1) * 16 + row;
#pragma unroll
      for (int r4 = 0; r4 < 4; ++r4) {
        const int grow = growb + r4;
        float v = acc[mf][nf][r4];
        if constexpr (EPI == 0) {
          o_f32[(size_t)grow * N + gcol] = v;
        } else {
          if (gcol < 2048) o_b16a[(size_t)grow * 2048 + gcol] = f2bf(v);
          else             o_b16b[(size_t)grow * 2048 + (gcol - 2048)] = f2bf(v);
        }
      }
    }
  }
}

// ---------------------------------------------------------------------------
// 128-class GEMM (R5 3-buffer structure) for the small/skinny GEMMs.
// ---------------------------------------------------------------------------
template <int BM, int BN, int WM, int WN, int EPI>
__global__ __launch_bounds__(256) void gemm_bt_kernel(
    const u16* __restrict__ A, const u16* __restrict__ Bw,
    int M, int N, int Kd,
    float* __restrict__ o_f32, u16* __restrict__ o_b16a,
    u16* __restrict__ o_b16b, const float* __restrict__ bias,
    float* __restrict__ oB, float* __restrict__ oC)
{
  constexpr int MFR = BM / WM / 16;
  constexpr int NFR = BN / WN / 16;
  constexpr int TA = BM * 4;
  constexpr int TB = BN * 4;
  constexpr int TILE = (BM + BN) * 32;
  constexpr int LA3 = (TA > 192) ? ((TA - 193) / 256 + 1) : 0;
  constexpr int LB3 = (TB > 192) ? ((TB - 193) / 256 + 1) : 0;
  constexpr int LPS = LA3 + LB3;
  __shared__ u16 lds[TILE * 3];

  const int tid  = threadIdx.x;
  const int wave = tid >> 6;
  const int lane = tid & 63;
  const int row  = lane & 15;
  const int g    = lane >> 4;
  const int swz  = g ^ ((row >> 1) & 3);
  const int rowBase = blockIdx.y * BM;
  const int colBase = blockIdx.x * BN;
  const int WROW = (wave / WN) * (BM / WM);
  const int WCOL = (wave % WN) * (BN / WN);

  auto stage = [&](int kt, int bufbase) {
    const int kk = kt * 32;
#pragma unroll
    for (int c0 = 0; c0 < TA; c0 += 256) {
      int ch = c0 + tid;
      if (ch < TA) {
        int r = ch >> 2;
        int gs = (ch & 3) ^ ((r >> 1) & 3);
        gload_lds16(A + (size_t)(rowBase + r) * Kd + kk + gs * 8,
                    (void*)(lds + bufbase + (c0 + wave * 64) * 8));
      }
    }
#pragma unroll
    for (int c0 = 0; c0 < TB; c0 += 256) {
      int ch = c0 + tid;
      if (ch < TB) {
        int r = ch >> 2;
        int gs = (ch & 3) ^ ((r >> 1) & 3);
        gload_lds16(Bw + (size_t)(colBase + r) * Kd + kk + gs * 8,
                    (void*)(lds + bufbase + BM * 32 + (c0 + wave * 64) * 8));
      }
    }
  };

  f32x4 acc[MFR][NFR];
#pragma unroll
  for (int i = 0; i < MFR; ++i)
#pragma unroll
    for (int j = 0; j < NFR; ++j) acc[i][j] = (f32x4){0.f, 0.f, 0.f, 0.f};

  const int nt = Kd / 32;
  stage(0, 0);
  stage(1, TILE);
  int cur = 0;
  for (int t = 0; t < nt; ++t) {
    if (t + 2 < nt) {
      int b2 = cur + 2; if (b2 >= 3) b2 -= 3;
      stage(t + 2, b2 * TILE);
      wait_vmcnt<2 * LPS>();
    } else if (t + 1 < nt) {
      wait_vmcnt<LPS>();
    } else {
      wait_vmcnt<0>();
    }
    __builtin_amdgcn_sched_barrier(0);
    __builtin_amdgcn_s_barrier();
    __builtin_amdgcn_sched_barrier(0);
    const u16* lb = lds + cur * TILE;
    short8 af[MFR], bfr[NFR];
#pragma unroll
    for (int mi = 0; mi < MFR; ++mi)
      af[mi] = *(const short8*)(lb + (WROW + mi * 16 + row) * 32 + swz * 8);
#pragma unroll
    for (int ni = 0; ni < NFR; ++ni)
      bfr[ni] = *(const short8*)(lb + BM * 32 + (WCOL + ni * 16 + row) * 32 + swz * 8);
#pragma unroll
    for (int mi = 0; mi < MFR; ++mi)
#pragma unroll
      for (int ni = 0; ni < NFR; ++ni)
        mfma_bf16(acc[mi][ni], af[mi], bfr[ni]);
    __builtin_amdgcn_sched_barrier(0);
    __builtin_amdgcn_s_barrier();
    cur += 1; if (cur >= 3) cur -= 3;
  }

#pragma unroll
  for (int mi = 0; mi < MFR; ++mi) {
#pragma unroll
    for (int ni = 0; ni < NFR; ++ni) {
      const int gcol = colBase + WCOL + ni * 16 + row;
#pragma unroll
      for (int r = 0; r < 4; ++r) {
        const int grow = rowBase + WROW + mi * 16 + g * 4 + r;
        float v = acc[mi][ni][r];
        if constexpr (EPI == 0) {
          o_f32[(size_t)grow * N + gcol] = v;
        } else if constexpr (EPI == 1) {
          if (gcol < 2048) o_b16a[(size_t)grow * 2048 + gcol] = f2bf(v);
          else             o_b16b[(size_t)grow * 2048 + (gcol - 2048)] = f2bf(v);
        } else if constexpr (EPI == 2) {
          if (gcol < 64)      o_b16a[(size_t)grow * 64 + gcol] = f2bf(v);
          else if (gcol < 80) oB[(size_t)grow * 16 + (gcol - 64)] = v;
          else                oC[(size_t)grow * 16 + (gcol - 80)] = v;
        } else {
          float x = v + bias[gcol];
          o_f32[(size_t)grow * N + gcol] = (x > 20.f) ? x : __logf(1.f + __expf(x));
        }
      }
    }
  }
}

// ---------------------------------------------------------------------------
__global__ __launch_bounds__(256) void cvt_bf16_kernel(
    const float* __restrict__ in, u16* __restrict__ out, int n8)
{
  int i = blockIdx.x * 256 + threadIdx.x;
  if (i >= n8) return;
  const float4* p = (const float4*)(in + (size_t)i * 8);
  float4 a = p[0], b = p[1];
  float v[8] = {a.x, a.y, a.z, a.w, b.x, b.y, b.z, b.w};
  unsigned o[4];
#pragma unroll
  for (int q = 0; q < 4; ++q)
    o[q] = (unsigned)f2bf(v[2 * q]) | ((unsigned)f2bf(v[2 * q + 1]) << 16);
  *(uint4*)(out + (size_t)i * 8) = make_uint4(o[0], o[1], o[2], o[3]);
}

// ---------------------------------------------------------------------------
__global__ __launch_bounds__(256) void conv_silu_kernel(
    const u16* __restrict__ hsraw, const float* __restrict__ cw,
    const float* __restrict__ cb, u16* __restrict__ hsb)
{
  int idx = blockIdx.x * 256 + threadIdx.x;
  int e0 = (idx & 255) * 8;
  int t  = (idx >> 8) & 4095;
  int b  = idx >> 20;
  float acc[8];
  float wv[4][8];
#pragma unroll
  for (int j = 0; j < 8; ++j) acc[j] = cb[e0 + j];
#pragma unroll
  for (int k = 0; k < 4; ++k)
#pragma unroll
    for (int j = 0; j < 8; ++j) wv[k][j] = cw[(e0 + j) * 4 + k];
#pragma unroll
  for (int k = 0; k < 4; ++k) {
    int tt = t - 3 + k;
    if (tt < 0) continue;
    uint4 v4 = *(const uint4*)(hsraw + ((size_t)(b * 4096 + tt)) * 2048 + e0);
    unsigned arr[4] = {v4.x, v4.y, v4.z, v4.w};
#pragma unroll
    for (int q = 0; q < 4; ++q) {
      acc[2 * q]     += wv[k][2 * q]     * bf2f((u16)(arr[q] & 0xffffu));
      acc[2 * q + 1] += wv[k][2 * q + 1] * bf2f((u16)(arr[q] >> 16));
    }
  }
  unsigned o[4];
#pragma unroll
  for (int q = 0; q < 4; ++q) {
    float a0 = acc[2 * q], a1 = acc[2 * q + 1];
    a0 = a0 / (1.f + __expf(-a0));
    a1 = a1 / (1.f + __expf(-a1));
    o[q] = (unsigned)f2bf(a0) | ((unsigned)f2bf(a1) << 16);
  }
  *(uint4*)(hsb + ((size_t)(b * 4096 + t)) * 2048 + e0) = make_uint4(o[0], o[1], o[2], o[3]);
}

// ---------------------------------------------------------------------------
// 3-phase chunked selective scan (C=64 chunks of 64 steps).
// ---------------------------------------------------------------------------
__global__ __launch_bounds__(256) void scan_phase1(
    const float* __restrict__ delta, const u16* __restrict__ hsb,
    const float* __restrict__ Bb, const float* __restrict__ alog,
    float* __restrict__ h_end, float* __restrict__ Ssum)
{
  __shared__ __align__(16) float Bs[64 * 16];
  const int tid = threadIdx.x;
  const int e = blockIdx.x * 256 + tid;
  const int c = blockIdx.y;
  const int b = blockIdx.z;
  const int t0 = c * 64;
  {
    const float* src = Bb + ((size_t)(b * 4096 + t0)) * 16;
#pragma unroll
    for (int k = 0; k < 4; ++k) Bs[tid + k * 256] = src[tid + k * 256];
  }
  float An[16];
  {
    const float4* ap = (const float4*)(alog + e * 16);
#pragma unroll
    for (int q = 0; q < 4; ++q) {
      float4 v = ap[q];
      An[4*q+0] = -__expf(v.x); An[4*q+1] = -__expf(v.y);
      An[4*q+2] = -__expf(v.z); An[4*q+3] = -__expf(v.w);
    }
  }
  __syncthreads();
  float h[16];
#pragma unroll
  for (int n = 0; n < 16; ++n) h[n] = 0.f;
  float sumd = 0.f;
  size_t base = ((size_t)(b * 4096 + t0)) * 2048 + e;
  float dd = delta[base];
  float uu = bf2f(hsb[base]);
  for (int j = 0; j < 64; ++j) {
    int jn = (j < 63) ? j + 1 : 63;
    float d_nxt = delta[base + (size_t)jn * 2048];
    float u_nxt = bf2f(hsb[base + (size_t)jn * 2048]);
    const float4* Bv = (const float4*)(Bs + j * 16);
    float4 b0 = Bv[0], b1 = Bv[1], b2 = Bv[2], b3 = Bv[3];
    float Bl[16] = {b0.x,b0.y,b0.z,b0.w, b1.x,b1.y,b1.z,b1.w,
                    b2.x,b2.y,b2.z,b2.w, b3.x,b3.y,b3.z,b3.w};
    sumd += dd;
    float du = dd * uu;
#pragma unroll
    for (int n = 0; n < 16; ++n)
      h[n] = fmaf(__expf(An[n] * dd), h[n], du * Bl[n]);
    dd = d_nxt; uu = u_nxt;
  }
  float* he = h_end + (((size_t)(b * 2048 + e)) * 64 + c) * 16;
#pragma unroll
  for (int q = 0; q < 4; ++q) {
    float4 v = {h[4*q], h[4*q+1], h[4*q+2], h[4*q+3]};
    *(float4*)(he + 4 * q) = v;
  }
  Ssum[((size_t)(b * 2048 + e)) * 64 + c] = sumd;
}

__global__ __launch_bounds__(256) void scan_phase2(
    const float* __restrict__ h_end, const float* __restrict__ Ssum,
    const float* __restrict__ alog, float* __restrict__ h_start)
{
  const int tid = threadIdx.x;
  const int n = tid & 15;
  const int G = blockIdx.x * 16 + (tid >> 4);
  const int e = G & 2047;
  const float An = -__expf(alog[e * 16 + n]);
  size_t hb = (size_t)G * 64 * 16 + n;
  size_t sb = (size_t)G * 64;
  float h = 0.f;
  constexpr int PF = 8;
  float hq[PF], Sq[PF];
#pragma unroll
  for (int j = 0; j < PF; ++j) { hq[j] = h_end[hb + (size_t)j * 16]; Sq[j] = Ssum[sb + j]; }
  for (int c0 = 0; c0 < 64; c0 += PF) {
    float hn[PF], Sn[PF];
#pragma unroll
    for (int j = 0; j < PF; ++j) {
      int cn = c0 + PF + j; cn = (cn < 64) ? cn : 63;
      hn[j] = h_end[hb + (size_t)cn * 16]; Sn[j] = Ssum[sb + cn];
    }
#pragma unroll
    for (int j = 0; j < PF; ++j) {
      h_start[hb + (size_t)(c0 + j) * 16] = h;
      h = fmaf(__expf(An * Sq[j]), h, hq[j]);
    }
#pragma unroll
    for (int j = 0; j < PF; ++j) { hq[j] = hn[j]; Sq[j] = Sn[j]; }
  }
}

__global__ __launch_bounds__(256) void scan_phase3(
    const float* __restrict__ delta, const u16* __restrict__ hsb,
    const float* __restrict__ Bb, const float* __restrict__ Cb,
    const float* __restrict__ alog, const float* __restrict__ h_start,
    const float* __restrict__ Dv, u16* __restrict__ gate_y2)
{
  __shared__ __align__(16) float Bs[64 * 16];
  __shared__ __align__(16) float Cs[64 * 16];
  const int tid = threadIdx.x;
  const int e = blockIdx.x * 256 + tid;
  const int c = blockIdx.y;
  const int b = blockIdx.z;
  const int t0 = c * 64;
  {
    const float* srcB = Bb + ((size_t)(b * 4096 + t0)) * 16;
    const float* srcC = Cb + ((size_t)(b * 4096 + t0)) * 16;
#pragma unroll
    for (int k = 0; k < 4; ++k) {
      Bs[tid + k * 256] = srcB[tid + k * 256];
      Cs[tid + k * 256] = srcC[tid + k * 256];
    }
  }
  float An[16];
  {
    const float4* ap = (const float4*)(alog + e * 16);
#pragma unroll
    for (int q = 0; q < 4; ++q) {
      float4 v = ap[q];
      An[4*q+0] = -__expf(v.x); An[4*q+1] = -__expf(v.y);
      An[4*q+2] = -__expf(v.z); An[4*q+3] = -__expf(v.w);
    }
  }
  const float De = Dv[e];
  float h[16];
  {
    const float4* hp = (const float4*)(h_start + (((size_t)(b * 2048 + e)) * 64 + c) * 16);
#pragma unroll
    for (int q = 0; q < 4; ++q) {
      float4 v = hp[q];
      h[4*q+0] = v.x; h[4*q+1] = v.y; h[4*q+2] = v.z; h[4*q+3] = v.w;
    }
  }
  __syncthreads();
  size_t base = ((size_t)(b * 4096 + t0)) * 2048 + e;
  float dd = delta[base];
  float uu = bf2f(hsb[base]);
  float gg = bf2f(gate_y2[base]);
  for (int j = 0; j < 64; ++j) {
    int jn = (j < 63) ? j + 1 : 63;
    float d_nxt = delta[base + (size_t)jn * 2048];
    float u_nxt = bf2f(hsb[base + (size_t)jn * 2048]);
    float g_nxt = bf2f(gate_y2[base + (size_t)jn * 2048]);
    const float4* Bv = (const float4*)(Bs + j * 16);
    const float4* Cv = (const float4*)(Cs + j * 16);
    float4 b0 = Bv[0], b1 = Bv[1], b2 = Bv[2], b3 = Bv[3];
    float4 c0v = Cv[0], c1v = Cv[1], c2v = Cv[2], c3v = Cv[3];
    float Bl[16] = {b0.x,b0.y,b0.z,b0.w, b1.x,b1.y,b1.z,b1.w,
                    b2.x,b2.y,b2.z,b2.w, b3.x,b3.y,b3.z,b3.w};
    float Cl[16] = {c0v.x,c0v.y,c0v.z,c0v.w, c1v.x,c1v.y,c1v.z,c1v.w,
                    c2v.x,c2v.y,c2v.z,c2v.w, c3v.x,c3v.y,c3v.z,c3v.w};
    float du = dd * uu;
    float y = 0.f;
#pragma unroll
    for (int n = 0; n < 16; ++n) {
      h[n] = fmaf(__expf(An[n] * dd), h[n], du * Bl[n]);
      y = fmaf(h[n], Cl[n], y);
    }
    float val = (y + uu * De) * (gg / (1.f + __expf(-gg)));
    gate_y2[base + (size_t)j * 2048] = f2bf(val);
    dd = d_nxt; uu = u_nxt; gg = g_nxt;
  }
}

// ---------------------------------------------------------------------------
extern "C" void kernel_launch(void* const* d_in, const int* in_sizes, int n_in,
                              void* d_out, int out_size, void* d_ws, size_t ws_size,
                              hipStream_t stream)
{
  const float* x    = (const float*)d_in[0];
  const float* w1   = (const float*)d_in[1];
  const float* cw   = (const float*)d_in[2];
  const float* cb   = (const float*)d_in[3];
  const float* xp   = (const float*)d_in[4];
  const float* dtw  = (const float*)d_in[5];
  const float* dtb  = (const float*)d_in[6];
  const float* alog = (const float*)d_in[7];
  const float* Dp   = (const float*)d_in[8];
  const float* wo   = (const float*)d_in[9];
  float* out = (float*)d_out;
  char* ws = (char*)d_ws;

  const size_t o_xb    = 0;           // 16 MB  x bf16 (reused: h_end fp32)
  const size_t o_wb1   = 16777216;    //  8 MB  in_proj_w bf16
  const size_t o_xpb   = 25165824;    //  .4MB  x_proj_w bf16
  const size_t o_dtwb  = 25559040;    //  .25MB dt_w bf16
  const size_t o_wob   = 25821184;    //  4 MB  out_proj_w bf16
  const size_t o_hsraw = 30015488;    // 32 MB  pre-conv hs (reused: h_start+Ssum)
  const size_t o_gate  = 63569920;    // 32 MB  gate bf16 (y2 written in place)
  const size_t o_hsb   = 97124352;    // 32 MB  post-conv hs bf16
  const size_t o_dtrb  = 130678784;   //  1 MB  dtr bf16
  const size_t o_Bb    = 131727360;   //  .5MB  B fp32
  const size_t o_Cb    = 132251648;   //  .5MB  C fp32
  const size_t o_delta = 132775936;   // 64 MB  delta fp32
  const size_t WS_NEED = o_delta + 67108864 + 262144;
  if (ws_size < WS_NEED) return;

  u16* xb    = (u16*)(ws + o_xb);
  u16* wb1   = (u16*)(ws + o_wb1);
  u16* xpb   = (u16*)(ws + o_xpb);
  u16* dtwb  = (u16*)(ws + o_dtwb);
  u16* wob   = (u16*)(ws + o_wob);
  u16* hsraw = (u16*)(ws + o_hsraw);
  u16* gate  = (u16*)(ws + o_gate);
  u16* hsb   = (u16*)(ws + o_hsb);
  u16* dtrb  = (u16*)(ws + o_dtrb);
  float* Bb    = (float*)(ws + o_Bb);
  float* Cb    = (float*)(ws + o_Cb);
  float* delta = (float*)(ws + o_delta);
  float* h_end   = (float*)(ws + o_xb);
  float* h_start = (float*)(ws + o_hsraw);
  float* Ssum    = (float*)(ws + o_hsraw + 16777216);

  cvt_bf16_kernel<<<4096, 256, 0, stream>>>(x,   xb,   1048576);
  cvt_bf16_kernel<<<2048, 256, 0, stream>>>(w1,  wb1,  524288);
  cvt_bf16_kernel<<<96,   256, 0, stream>>>(xp,  xpb,  24576);
  cvt_bf16_kernel<<<64,   256, 0, stream>>>(dtw, dtwb, 16384);
  cvt_bf16_kernel<<<1024, 256, 0, stream>>>(wo,  wob,  262144);

  // GEMM1 (8-phase 256^2): grid = (8192/256)*(4096/256) = 512 blocks
  gemm256_kernel<1><<<512, 512, 0, stream>>>(
      xb, wb1, 8192, 4096, 1024, nullptr, hsraw, gate);
  conv_silu_kernel<<<8192, 256, 0, stream>>>(hsraw, cw, cb, hsb);
  gemm_bt_kernel<32,96,2,2,2><<<dim3(1,256), 256, 0, stream>>>(
      hsb, xpb, 8192, 96, 2048, nullptr, dtrb, nullptr, nullptr, Bb, Cb);
  gemm_bt_kernel<64,64,2,2,3><<<dim3(32,128), 256, 0, stream>>>(
      dtrb, dtwb, 8192, 2048, 64, delta, nullptr, nullptr, dtb, nullptr, nullptr);

  scan_phase1<<<dim3(8, 64, 2), 256, 0, stream>>>(delta, hsb, Bb, alog, h_end, Ssum);
  scan_phase2<<<256, 256, 0, stream>>>(h_end, Ssum, alog, h_start);
  scan_phase3<<<dim3(8, 64, 2), 256, 0, stream>>>(
      delta, hsb, Bb, Cb, alog, h_start, Dp, gate);

  gemm_bt_kernel<128,128,2,2,0><<<dim3(8,64), 256, 0, stream>>>(
      gate, wob, 8192, 1024, 2048, out, nullptr, nullptr, nullptr, nullptr, nullptr);
}

// Round 7
// 376.313 us; speedup vs baseline: 2.9188x; 1.0006x over previous
//
#include <hip/hip_runtime.h>

// Mamba mixer forward, MI355X. B=2 L=4096 H=1024 ED=2048 N=16 R=64 K=4.
// Pipeline: cvt(fp32->bf16) -> GEMM1(in_proj, 256^2 8-phase, split hs/gate) ->
// conv1d+SiLU -> GEMM2(x_proj) -> GEMM3(dt_proj + fast softplus) ->
// 3-phase chunked selective scan (fp32, gate/D/silu fused into phase3) ->
// GEMM4(out_proj) -> fp32.
//
// R7: gemm256 phases restructured so ds_read/stage/MFMA share ONE scheduling
// region (compiler interleaves; m196 mechanism). Leading bar+sched_barrier,
// trailing lgkmcnt(0)+sched_barrier; vmcnt(6) at END of P4/P8 before the next
// barrier (own-wait + barrier => all-waves guarantee). 8 barriers/iter.

typedef float f32x4 __attribute__((ext_vector_type(4)));
typedef short short8 __attribute__((ext_vector_type(8)));
typedef unsigned short u16;

#define DEV __device__ __forceinline__

DEV float bf2f(u16 u) {
  union { unsigned int i; float f; } v; v.i = ((unsigned int)u) << 16; return v.f;
}
DEV u16 f2bf(float f) {
  union { float f; unsigned int i; } v; v.f = f;
  return (u16)((v.i + 0x7fffu + ((v.i >> 16) & 1u)) >> 16);
}

DEV void gload_lds16(const void* g, void* l) {
  __builtin_amdgcn_global_load_lds(
      (const __attribute__((address_space(1))) unsigned int*)g,
      (__attribute__((address_space(3))) unsigned int*)l, 16, 0, 0);
}

DEV void mfma_bf16(f32x4& d, short8 a, short8 b) {
  asm("v_mfma_f32_16x16x32_bf16 %0, %1, %2, %0" : "+v"(d) : "v"(a), "v"(b));
}

template <int N> DEV void wait_vmcnt() {
  if constexpr (N == 0)      asm volatile("s_waitcnt vmcnt(0)" ::: "memory");
  else if constexpr (N == 1) asm volatile("s_waitcnt vmcnt(1)" ::: "memory");
  else if constexpr (N == 2) asm volatile("s_waitcnt vmcnt(2)" ::: "memory");
  else if constexpr (N == 4) asm volatile("s_waitcnt vmcnt(4)" ::: "memory");
  else if constexpr (N == 6) asm volatile("s_waitcnt vmcnt(6)" ::: "memory");
  else                       asm volatile("s_waitcnt vmcnt(8)" ::: "memory");
}

// phase start: barrier, then fence so nothing hoists above it
#define PH_PRE() do { __builtin_amdgcn_s_barrier(); \
  __builtin_amdgcn_sched_barrier(0); \
  __builtin_amdgcn_s_setprio(1); } while (0)
// phase end: drain own ds_reads (so next phase's stages can't overwrite
// LDS that any wave still reads), fence
#define PH_POST() do { __builtin_amdgcn_s_setprio(0); \
  asm volatile("s_waitcnt lgkmcnt(0)" ::: "memory"); \
  __builtin_amdgcn_sched_barrier(0); } while (0)

// ---------------------------------------------------------------------------
// 256x256 8-phase GEMM: C[M,N] = A[M,K] * B[N,K]^T, bf16 in, fp32 accum.
// 512 thr = 8 waves (2M x 4N), BK=64, 2 K-tiles/iter, LDS 128KB (2 parities).
// Per phase: {stage half-tile + ds_read subtile + 16 MFMA} in one region.
// vmcnt(6) at end of P4/P8: oldest-8 = next parity's 8 half-tile loads.
// ---------------------------------------------------------------------------
template <int EPI>
__global__ __launch_bounds__(512, 2) void gemm256_kernel(
    const u16* __restrict__ A, const u16* __restrict__ Bw,
    int M, int N, int Kd,
    float* __restrict__ o_f32, u16* __restrict__ o_b16a, u16* __restrict__ o_b16b)
{
  __shared__ u16 lds[65536];  // 128 KB
  const int tid  = threadIdx.x;
  const int wave = tid >> 6;
  const int lane = tid & 63;
  const int row  = lane & 15;
  const int g    = lane >> 4;
  const int wr   = wave >> 2;   // 0..1 (M)
  const int wc   = wave & 3;    // 0..3 (N)

  const int nbx = N >> 8;
  const int nwg = gridDim.x;
  const int cpx = nwg >> 3;
  const int swzb = (blockIdx.x & 7) * cpx + (blockIdx.x >> 3);
  const int bx = swzb % nbx, by = swzb / nbx;
  const int rowBase = by * 256, colBase = bx * 256;

  auto STAGE = [&](int isB, int h, int kt) {
    const u16* src = isB ? Bw : A;
    const int baseRow = (isB ? colBase : rowBase) + h * 128;
    const int ldsbase = (kt & 1) * 32768 + isB * 16384 + h * 8192;
    const int kk = kt * 64;
#pragma unroll
    for (int q = 0; q < 2; ++q) {
      int c = q * 512 + tid;
      int r = c >> 3;
      int qc = (c & 7) ^ (r & 7);
      gload_lds16(src + (size_t)(baseRow + r) * Kd + kk + qc * 8,
                  (void*)(lds + ldsbase + (q * 512 + wave * 64) * 8));
    }
  };

  f32x4 acc[8][4];
#pragma unroll
  for (int i = 0; i < 8; ++i)
#pragma unroll
    for (int j = 0; j < 4; ++j) acc[i][j] = (f32x4){0.f, 0.f, 0.f, 0.f};

  short8 rA[8], rB0[4], rB1[4];

#define LDA(PAR, MH) do { \
  _Pragma("unroll") for (int mi = 0; mi < 4; ++mi) \
  _Pragma("unroll") for (int ks = 0; ks < 2; ++ks) \
    rA[mi*2+ks] = *(const short8*)(lds + (PAR)*32768 + wr*8192 \
        + ((MH)*64 + mi*16 + row)*64 + (((ks*4 + g) ^ (row & 7))*8)); \
} while (0)

#define LDB(PAR, NH, RB) do { \
  _Pragma("unroll") for (int ni = 0; ni < 2; ++ni) \
  _Pragma("unroll") for (int ks = 0; ks < 2; ++ks) \
    (RB)[ni*2+ks] = *(const short8*)(lds + (PAR)*32768 + 16384 + (wc>>1)*8192 \
        + (((wc&1)*64 + (NH)*32 + ni*16 + row)*64) + (((ks*4 + g) ^ (row & 7))*8)); \
} while (0)

// ks-outer: 8 independent MFMAs between dependent same-acc pairs
#define QUAD(MH, NH, RB) do { \
  _Pragma("unroll") for (int ks = 0; ks < 2; ++ks) \
  _Pragma("unroll") for (int mi = 0; mi < 4; ++mi) \
  _Pragma("unroll") for (int ni = 0; ni < 2; ++ni) \
    mfma_bf16(acc[(MH)*4+mi][(NH)*2+ni], rA[mi*2+ks], (RB)[ni*2+ks]); \
} while (0)

  const int nkt = Kd >> 6;
  const int niters = nkt >> 1;

  // prologue: kt0 (4 halves) + B01(kt1) + A0(kt1); vmcnt(6) -> kt0 resident.
  STAGE(0, 0, 0); STAGE(0, 1, 0); STAGE(1, 0, 0); STAGE(1, 1, 0);
  STAGE(1, 0, 1); STAGE(1, 1, 1); STAGE(0, 0, 1);
  wait_vmcnt<6>();

  for (int i = 0; i < niters; ++i) {
    const int kt0 = 2 * i, kt1 = 2 * i + 1;
    const bool pf = (i + 1 < niters);
    // P1: stage A1(kt1) || read A(p0,mh0)+B(p0,n0) || QUAD(0,0)
    PH_PRE();
    STAGE(0, 1, kt1);
    LDB(0, 0, rB0); LDA(0, 0);
    QUAD(0, 0, rB0);
    PH_POST();
    // P2: read B(p0,n1) || QUAD(0,1)
    PH_PRE();
    LDB(0, 1, rB1);
    QUAD(0, 1, rB1);
    PH_POST();
    // P3: stage B01(kt0+2) || read A(p0,mh1) || QUAD(1,0)
    PH_PRE();
    if (pf) { STAGE(1, 0, kt0 + 2); STAGE(1, 1, kt0 + 2); }
    LDA(0, 1);
    QUAD(1, 0, rB0);
    PH_POST();
    // P4: stage A0(kt0+2) || QUAD(1,1); then vmcnt(6) -> kt1 resident
    PH_PRE();
    if (pf) STAGE(0, 0, kt0 + 2);
    QUAD(1, 1, rB1);
    PH_POST();
    if (pf) wait_vmcnt<6>(); else wait_vmcnt<0>();
    // P5: stage A1(kt0+2) || read A(p1,mh0)+B(p1,n0) || QUAD(0,0)
    PH_PRE();
    if (pf) STAGE(0, 1, kt0 + 2);
    LDB(1, 0, rB0); LDA(1, 0);
    QUAD(0, 0, rB0);
    PH_POST();
    // P6: read B(p1,n1) || QUAD(0,1)
    PH_PRE();
    LDB(1, 1, rB1);
    QUAD(0, 1, rB1);
    PH_POST();
    // P7: stage B01(kt1+2) || read A(p1,mh1) || QUAD(1,0)
    PH_PRE();
    if (pf) { STAGE(1, 0, kt1 + 2); STAGE(1, 1, kt1 + 2); }
    LDA(1, 1);
    QUAD(1, 0, rB0);
    PH_POST();
    // P8: stage A0(kt1+2) || QUAD(1,1); then vmcnt(6) -> next kt0 resident
    PH_PRE();
    if (pf) STAGE(0, 0, kt1 + 2);
    QUAD(1, 1, rB1);
    PH_POST();
    if (pf) wait_vmcnt<6>(); else wait_vmcnt<0>();
  }
#undef LDA
#undef LDB
#undef QUAD

  // epilogue: C/D layout col=lane&15, row=4*(lane>>4)+reg
#pragma unroll
  for (int mf = 0; mf < 8; ++mf) {
    const int growb = rowBase + wr * 128 + (mf >> 2) * 64 + (mf & 3) * 16 + g * 4;
#pragma unroll
    for (int nf = 0; nf < 4; ++nf) {
      const int gcol = colBase + wc * 64 + (nf >> 1) * 32 + (nf & 1) * 16 + row;
#pragma unroll
      for (int r4 = 0; r4 < 4; ++r4) {
        const int grow = growb + r4;
        float v = acc[mf][nf][r4];
        if constexpr (EPI == 0) {
          o_f32[(size_t)grow * N + gcol] = v;
        } else {
          if (gcol < 2048) o_b16a[(size_t)grow * 2048 + gcol] = f2bf(v);
          else             o_b16b[(size_t)grow * 2048 + (gcol - 2048)] = f2bf(v);
        }
      }
    }
  }
}

// ---------------------------------------------------------------------------
// 128-class GEMM (3-buffer counted) for the small/skinny GEMMs.
// ---------------------------------------------------------------------------
template <int BM, int BN, int WM, int WN, int EPI>
__global__ __launch_bounds__(256) void gemm_bt_kernel(
    const u16* __restrict__ A, const u16* __restrict__ Bw,
    int M, int N, int Kd,
    float* __restrict__ o_f32, u16* __restrict__ o_b16a,
    u16* __restrict__ o_b16b, const float* __restrict__ bias,
    float* __restrict__ oB, float* __restrict__ oC)
{
  constexpr int MFR = BM / WM / 16;
  constexpr int NFR = BN / WN / 16;
  constexpr int TA = BM * 4;
  constexpr int TB = BN * 4;
  constexpr int TILE = (BM + BN) * 32;
  constexpr int LA3 = (TA > 192) ? ((TA - 193) / 256 + 1) : 0;
  constexpr int LB3 = (TB > 192) ? ((TB - 193) / 256 + 1) : 0;
  constexpr int LPS = LA3 + LB3;
  __shared__ u16 lds[TILE * 3];

  const int tid  = threadIdx.x;
  const int wave = tid >> 6;
  const int lane = tid & 63;
  const int row  = lane & 15;
  const int g    = lane >> 4;
  const int swz  = g ^ ((row >> 1) & 3);
  const int rowBase = blockIdx.y * BM;
  const int colBase = blockIdx.x * BN;
  const int WROW = (wave / WN) * (BM / WM);
  const int WCOL = (wave % WN) * (BN / WN);

  auto stage = [&](int kt, int bufbase) {
    const int kk = kt * 32;
#pragma unroll
    for (int c0 = 0; c0 < TA; c0 += 256) {
      int ch = c0 + tid;
      if (ch < TA) {
        int r = ch >> 2;
        int gs = (ch & 3) ^ ((r >> 1) & 3);
        gload_lds16(A + (size_t)(rowBase + r) * Kd + kk + gs * 8,
                    (void*)(lds + bufbase + (c0 + wave * 64) * 8));
      }
    }
#pragma unroll
    for (int c0 = 0; c0 < TB; c0 += 256) {
      int ch = c0 + tid;
      if (ch < TB) {
        int r = ch >> 2;
        int gs = (ch & 3) ^ ((r >> 1) & 3);
        gload_lds16(Bw + (size_t)(colBase + r) * Kd + kk + gs * 8,
                    (void*)(lds + bufbase + BM * 32 + (c0 + wave * 64) * 8));
      }
    }
  };

  f32x4 acc[MFR][NFR];
#pragma unroll
  for (int i = 0; i < MFR; ++i)
#pragma unroll
    for (int j = 0; j < NFR; ++j) acc[i][j] = (f32x4){0.f, 0.f, 0.f, 0.f};

  const int nt = Kd / 32;
  stage(0, 0);
  stage(1, TILE);
  int cur = 0;
  for (int t = 0; t < nt; ++t) {
    if (t + 2 < nt) {
      int b2 = cur + 2; if (b2 >= 3) b2 -= 3;
      stage(t + 2, b2 * TILE);
      wait_vmcnt<2 * LPS>();
    } else if (t + 1 < nt) {
      wait_vmcnt<LPS>();
    } else {
      wait_vmcnt<0>();
    }
    __builtin_amdgcn_sched_barrier(0);
    __builtin_amdgcn_s_barrier();
    __builtin_amdgcn_sched_barrier(0);
    const u16* lb = lds + cur * TILE;
    short8 af[MFR], bfr[NFR];
#pragma unroll
    for (int mi = 0; mi < MFR; ++mi)
      af[mi] = *(const short8*)(lb + (WROW + mi * 16 + row) * 32 + swz * 8);
#pragma unroll
    for (int ni = 0; ni < NFR; ++ni)
      bfr[ni] = *(const short8*)(lb + BM * 32 + (WCOL + ni * 16 + row) * 32 + swz * 8);
#pragma unroll
    for (int mi = 0; mi < MFR; ++mi)
#pragma unroll
      for (int ni = 0; ni < NFR; ++ni)
        mfma_bf16(acc[mi][ni], af[mi], bfr[ni]);
    __builtin_amdgcn_sched_barrier(0);
    __builtin_amdgcn_s_barrier();
    cur += 1; if (cur >= 3) cur -= 3;
  }

#pragma unroll
  for (int mi = 0; mi < MFR; ++mi) {
#pragma unroll
    for (int ni = 0; ni < NFR; ++ni) {
      const int gcol = colBase + WCOL + ni * 16 + row;
#pragma unroll
      for (int r = 0; r < 4; ++r) {
        const int grow = rowBase + WROW + mi * 16 + g * 4 + r;
        float v = acc[mi][ni][r];
        if constexpr (EPI == 0) {
          o_f32[(size_t)grow * N + gcol] = v;
        } else if constexpr (EPI == 1) {
          if (gcol < 2048) o_b16a[(size_t)grow * 2048 + gcol] = f2bf(v);
          else             o_b16b[(size_t)grow * 2048 + (gcol - 2048)] = f2bf(v);
        } else if constexpr (EPI == 2) {
          if (gcol < 64)      o_b16a[(size_t)grow * 64 + gcol] = f2bf(v);
          else if (gcol < 80) oB[(size_t)grow * 16 + (gcol - 64)] = v;
          else                oC[(size_t)grow * 16 + (gcol - 80)] = v;
        } else {
          float x = v + bias[gcol];
          o_f32[(size_t)grow * N + gcol] = (x > 20.f) ? x : __logf(1.f + __expf(x));
        }
      }
    }
  }
}

// ---------------------------------------------------------------------------
DEV void cvt8(const float* in, u16* out, int j) {
  const float4* p = (const float4*)(in + (size_t)j * 8);
  float4 a = p[0], b = p[1];
  float v[8] = {a.x, a.y, a.z, a.w, b.x, b.y, b.z, b.w};
  unsigned o[4];
#pragma unroll
  for (int q = 0; q < 4; ++q)
    o[q] = (unsigned)f2bf(v[2 * q]) | ((unsigned)f2bf(v[2 * q + 1]) << 16);
  *(uint4*)(out + (size_t)j * 8) = make_uint4(o[0], o[1], o[2], o[3]);
}

__global__ __launch_bounds__(256) void cvt_bf16_kernel(
    const float* __restrict__ in, u16* __restrict__ out, int n8)
{
  int i = blockIdx.x * 256 + threadIdx.x;
  if (i >= n8) return;
  cvt8(in, out, i);
}

// fused convert of the 4 weight tensors (single launch)
__global__ __launch_bounds__(256) void cvt4_kernel(
    const float* __restrict__ a0, u16* __restrict__ o0, int n0,
    const float* __restrict__ a1, u16* __restrict__ o1, int n1,
    const float* __restrict__ a2, u16* __restrict__ o2, int n2,
    const float* __restrict__ a3, u16* __restrict__ o3, int n3)
{
  int i = blockIdx.x * 256 + threadIdx.x;
  if (i < n0)                { cvt8(a0, o0, i); return; }
  i -= n0;
  if (i < n1)                { cvt8(a1, o1, i); return; }
  i -= n1;
  if (i < n2)                { cvt8(a2, o2, i); return; }
  i -= n2;
  if (i < n3)                { cvt8(a3, o3, i); }
}

// ---------------------------------------------------------------------------
__global__ __launch_bounds__(256) void conv_silu_kernel(
    const u16* __restrict__ hsraw, const float* __restrict__ cw,
    const float* __restrict__ cb, u16* __restrict__ hsb)
{
  int idx = blockIdx.x * 256 + threadIdx.x;
  int e0 = (idx & 255) * 8;
  int t  = (idx >> 8) & 4095;
  int b  = idx >> 20;
  float acc[8];
  float wv[4][8];
#pragma unroll
  for (int j = 0; j < 8; ++j) acc[j] = cb[e0 + j];
#pragma unroll
  for (int k = 0; k < 4; ++k)
#pragma unroll
    for (int j = 0; j < 8; ++j) wv[k][j] = cw[(e0 + j) * 4 + k];
#pragma unroll
  for (int k = 0; k < 4; ++k) {
    int tt = t - 3 + k;
    if (tt < 0) continue;
    uint4 v4 = *(const uint4*)(hsraw + ((size_t)(b * 4096 + tt)) * 2048 + e0);
    unsigned arr[4] = {v4.x, v4.y, v4.z, v4.w};
#pragma unroll
    for (int q = 0; q < 4; ++q) {
      acc[2 * q]     += wv[k][2 * q]     * bf2f((u16)(arr[q] & 0xffffu));
      acc[2 * q + 1] += wv[k][2 * q + 1] * bf2f((u16)(arr[q] >> 16));
    }
  }
  unsigned o[4];
#pragma unroll
  for (int q = 0; q < 4; ++q) {
    float a0 = acc[2 * q], a1 = acc[2 * q + 1];
    a0 = a0 / (1.f + __expf(-a0));
    a1 = a1 / (1.f + __expf(-a1));
    o[q] = (unsigned)f2bf(a0) | ((unsigned)f2bf(a1) << 16);
  }
  *(uint4*)(hsb + ((size_t)(b * 4096 + t)) * 2048 + e0) = make_uint4(o[0], o[1], o[2], o[3]);
}

// ---------------------------------------------------------------------------
// 3-phase chunked selective scan (C=64 chunks of 64 steps).
// ---------------------------------------------------------------------------
__global__ __launch_bounds__(256) void scan_phase1(
    const float* __restrict__ delta, const u16* __restrict__ hsb,
    const float* __restrict__ Bb, const float* __restrict__ alog,
    float* __restrict__ h_end, float* __restrict__ Ssum)
{
  __shared__ __align__(16) float Bs[64 * 16];
  const int tid = threadIdx.x;
  const int e = blockIdx.x * 256 + tid;
  const int c = blockIdx.y;
  const int b = blockIdx.z;
  const int t0 = c * 64;
  {
    const float* src = Bb + ((size_t)(b * 4096 + t0)) * 16;
#pragma unroll
    for (int k = 0; k < 4; ++k) Bs[tid + k * 256] = src[tid + k * 256];
  }
  float An[16];
  {
    const float4* ap = (const float4*)(alog + e * 16);
#pragma unroll
    for (int q = 0; q < 4; ++q) {
      float4 v = ap[q];
      An[4*q+0] = -__expf(v.x); An[4*q+1] = -__expf(v.y);
      An[4*q+2] = -__expf(v.z); An[4*q+3] = -__expf(v.w);
    }
  }
  __syncthreads();
  float h[16];
#pragma unroll
  for (int n = 0; n < 16; ++n) h[n] = 0.f;
  float sumd = 0.f;
  size_t base = ((size_t)(b * 4096 + t0)) * 2048 + e;
  float dd = delta[base];
  float uu = bf2f(hsb[base]);
  for (int j = 0; j < 64; ++j) {
    int jn = (j < 63) ? j + 1 : 63;
    float d_nxt = delta[base + (size_t)jn * 2048];
    float u_nxt = bf2f(hsb[base + (size_t)jn * 2048]);
    const float4* Bv = (const float4*)(Bs + j * 16);
    float4 b0 = Bv[0], b1 = Bv[1], b2 = Bv[2], b3 = Bv[3];
    float Bl[16] = {b0.x,b0.y,b0.z,b0.w, b1.x,b1.y,b1.z,b1.w,
                    b2.x,b2.y,b2.z,b2.w, b3.x,b3.y,b3.z,b3.w};
    sumd += dd;
    float du = dd * uu;
#pragma unroll
    for (int n = 0; n < 16; ++n)
      h[n] = fmaf(__expf(An[n] * dd), h[n], du * Bl[n]);
    dd = d_nxt; uu = u_nxt;
  }
  float* he = h_end + (((size_t)(b * 2048 + e)) * 64 + c) * 16;
#pragma unroll
  for (int q = 0; q < 4; ++q) {
    float4 v = {h[4*q], h[4*q+1], h[4*q+2], h[4*q+3]};
    *(float4*)(he + 4 * q) = v;
  }
  Ssum[((size_t)(b * 2048 + e)) * 64 + c] = sumd;
}

__global__ __launch_bounds__(256) void scan_phase2(
    const float* __restrict__ h_end, const float* __restrict__ Ssum,
    const float* __restrict__ alog, float* __restrict__ h_start)
{
  const int tid = threadIdx.x;
  const int n = tid & 15;
  const int G = blockIdx.x * 16 + (tid >> 4);
  const int e = G & 2047;
  const float An = -__expf(alog[e * 16 + n]);
  size_t hb = (size_t)G * 64 * 16 + n;
  size_t sb = (size_t)G * 64;
  float h = 0.f;
  constexpr int PF = 8;
  float hq[PF], Sq[PF];
#pragma unroll
  for (int j = 0; j < PF; ++j) { hq[j] = h_end[hb + (size_t)j * 16]; Sq[j] = Ssum[sb + j]; }
  for (int c0 = 0; c0 < 64; c0 += PF) {
    float hn[PF], Sn[PF];
#pragma unroll
    for (int j = 0; j < PF; ++j) {
      int cn = c0 + PF + j; cn = (cn < 64) ? cn : 63;
      hn[j] = h_end[hb + (size_t)cn * 16]; Sn[j] = Ssum[sb + cn];
    }
#pragma unroll
    for (int j = 0; j < PF; ++j) {
      h_start[hb + (size_t)(c0 + j) * 16] = h;
      h = fmaf(__expf(An * Sq[j]), h, hq[j]);
    }
#pragma unroll
    for (int j = 0; j < PF; ++j) { hq[j] = hn[j]; Sq[j] = Sn[j]; }
  }
}

__global__ __launch_bounds__(256) void scan_phase3(
    const float* __restrict__ delta, const u16* __restrict__ hsb,
    const float* __restrict__ Bb, const float* __restrict__ Cb,
    const float* __restrict__ alog, const float* __restrict__ h_start,
    const float* __restrict__ Dv, u16* __restrict__ gate_y2)
{
  __shared__ __align__(16) float Bs[64 * 16];
  __shared__ __align__(16) float Cs[64 * 16];
  const int tid = threadIdx.x;
  const int e = blockIdx.x * 256 + tid;
  const int c = blockIdx.y;
  const int b = blockIdx.z;
  const int t0 = c * 64;
  {
    const float* srcB = Bb + ((size_t)(b * 4096 + t0)) * 16;
    const float* srcC = Cb + ((size_t)(b * 4096 + t0)) * 16;
#pragma unroll
    for (int k = 0; k < 4; ++k) {
      Bs[tid + k * 256] = srcB[tid + k * 256];
      Cs[tid + k * 256] = srcC[tid + k * 256];
    }
  }
  float An[16];
  {
    const float4* ap = (const float4*)(alog + e * 16);
#pragma unroll
    for (int q = 0; q < 4; ++q) {
      float4 v = ap[q];
      An[4*q+0] = -__expf(v.x); An[4*q+1] = -__expf(v.y);
      An[4*q+2] = -__expf(v.z); An[4*q+3] = -__expf(v.w);
    }
  }
  const float De = Dv[e];
  float h[16];
  {
    const float4* hp = (const float4*)(h_start + (((size_t)(b * 2048 + e)) * 64 + c) * 16);
#pragma unroll
    for (int q = 0; q < 4; ++q) {
      float4 v = hp[q];
      h[4*q+0] = v.x; h[4*q+1] = v.y; h[4*q+2] = v.z; h[4*q+3] = v.w;
    }
  }
  __syncthreads();
  size_t base = ((size_t)(b * 4096 + t0)) * 2048 + e;
  float dd = delta[base];
  float uu = bf2f(hsb[base]);
  float gg = bf2f(gate_y2[base]);
  for (int j = 0; j < 64; ++j) {
    int jn = (j < 63) ? j + 1 : 63;
    float d_nxt = delta[base + (size_t)jn * 2048];
    float u_nxt = bf2f(hsb[base + (size_t)jn * 2048]);
    float g_nxt = bf2f(gate_y2[base + (size_t)jn * 2048]);
    const float4* Bv = (const float4*)(Bs + j * 16);
    const float4* Cv = (const float4*)(Cs + j * 16);
    float4 b0 = Bv[0], b1 = Bv[1], b2 = Bv[2], b3 = Bv[3];
    float4 c0v = Cv[0], c1v = Cv[1], c2v = Cv[2], c3v = Cv[3];
    float Bl[16] = {b0.x,b0.y,b0.z,b0.w, b1.x,b1.y,b1.z,b1.w,
                    b2.x,b2.y,b2.z,b2.w, b3.x,b3.y,b3.z,b3.w};
    float Cl[16] = {c0v.x,c0v.y,c0v.z,c0v.w, c1v.x,c1v.y,c1v.z,c1v.w,
                    c2v.x,c2v.y,c2v.z,c2v.w, c3v.x,c3v.y,c3v.z,c3v.w};
    float du = dd * uu;
    float y = 0.f;
#pragma unroll
    for (int n = 0; n < 16; ++n) {
      h[n] = fmaf(__expf(An[n] * dd), h[n], du * Bl[n]);
      y = fmaf(h[n], Cl[n], y);
    }
    float val = (y + uu * De) * (gg / (1.f + __expf(-gg)));
    gate_y2[base + (size_t)j * 2048] = f2bf(val);
    dd = d_nxt; uu = u_nxt; gg = g_nxt;
  }
}

// ---------------------------------------------------------------------------
extern "C" void kernel_launch(void* const* d_in, const int* in_sizes, int n_in,
                              void* d_out, int out_size, void* d_ws, size_t ws_size,
                              hipStream_t stream)
{
  const float* x    = (const float*)d_in[0];
  const float* w1   = (const float*)d_in[1];
  const float* cw   = (const float*)d_in[2];
  const float* cb   = (const float*)d_in[3];
  const float* xp   = (const float*)d_in[4];
  const float* dtw  = (const float*)d_in[5];
  const float* dtb  = (const float*)d_in[6];
  const float* alog = (const float*)d_in[7];
  const float* Dp   = (const float*)d_in[8];
  const float* wo   = (const float*)d_in[9];
  float* out = (float*)d_out;
  char* ws = (char*)d_ws;

  const size_t o_xb    = 0;           // 16 MB  x bf16 (reused: h_end fp32)
  const size_t o_wb1   = 16777216;    //  8 MB  in_proj_w bf16
  const size_t o_xpb   = 25165824;    //  .4MB  x_proj_w bf16
  const size_t o_dtwb  = 25559040;    //  .25MB dt_w bf16
  const size_t o_wob   = 25821184;    //  4 MB  out_proj_w bf16
  const size_t o_hsraw = 30015488;    // 32 MB  pre-conv hs (reused: h_start+Ssum)
  const size_t o_gate  = 63569920;    // 32 MB  gate bf16 (y2 written in place)
  const size_t o_hsb   = 97124352;    // 32 MB  post-conv hs bf16
  const size_t o_dtrb  = 130678784;   //  1 MB  dtr bf16
  const size_t o_Bb    = 131727360;   //  .5MB  B fp32
  const size_t o_Cb    = 132251648;   //  .5MB  C fp32
  const size_t o_delta = 132775936;   // 64 MB  delta fp32
  const size_t WS_NEED = o_delta + 67108864 + 262144;
  if (ws_size < WS_NEED) return;

  u16* xb    = (u16*)(ws + o_xb);
  u16* wb1   = (u16*)(ws + o_wb1);
  u16* xpb   = (u16*)(ws + o_xpb);
  u16* dtwb  = (u16*)(ws + o_dtwb);
  u16* wob   = (u16*)(ws + o_wob);
  u16* hsraw = (u16*)(ws + o_hsraw);
  u16* gate  = (u16*)(ws + o_gate);
  u16* hsb   = (u16*)(ws + o_hsb);
  u16* dtrb  = (u16*)(ws + o_dtrb);
  float* Bb    = (float*)(ws + o_Bb);
  float* Cb    = (float*)(ws + o_Cb);
  float* delta = (float*)(ws + o_delta);
  float* h_end   = (float*)(ws + o_xb);
  float* h_start = (float*)(ws + o_hsraw);
  float* Ssum    = (float*)(ws + o_hsraw + 16777216);

  cvt_bf16_kernel<<<4096, 256, 0, stream>>>(x, xb, 1048576);
  // fused weight converts: 524288 + 24576 + 16384 + 262144 = 827392 units
  cvt4_kernel<<<3232, 256, 0, stream>>>(
      w1, wb1, 524288, xp, xpb, 24576, dtw, dtwb, 16384, wo, wob, 262144);

  // GEMM1 (8-phase 256^2): grid = (8192/256)*(4096/256) = 512 blocks
  gemm256_kernel<1><<<512, 512, 0, stream>>>(
      xb, wb1, 8192, 4096, 1024, nullptr, hsraw, gate);
  conv_silu_kernel<<<8192, 256, 0, stream>>>(hsraw, cw, cb, hsb);
  gemm_bt_kernel<32,96,2,2,2><<<dim3(1,256), 256, 0, stream>>>(
      hsb, xpb, 8192, 96, 2048, nullptr, dtrb, nullptr, nullptr, Bb, Cb);
  gemm_bt_kernel<64,64,2,2,3><<<dim3(32,128), 256, 0, stream>>>(
      dtrb, dtwb, 8192, 2048, 64, delta, nullptr, nullptr, dtb, nullptr, nullptr);

  scan_phase1<<<dim3(8, 64, 2), 256, 0, stream>>>(delta, hsb, Bb, alog, h_end, Ssum);
  scan_phase2<<<256, 256, 0, stream>>>(h_end, Ssum, alog, h_start);
  scan_phase3<<<dim3(8, 64, 2), 256, 0, stream>>>(
      delta, hsb, Bb, Cb, alog, h_start, Dp, gate);

  gemm_bt_kernel<128,128,2,2,0><<<dim3(8,64), 256, 0, stream>>>(
      gate, wob, 8192, 1024, 2048, out, nullptr, nullptr, nullptr, nullptr, nullptr);
}